// Round 13
// baseline (277.642 us; speedup 1.0000x reference)
//
#include <hip/hip_runtime.h>
#include <hip/hip_bf16.h>
#include <math.h>

#define TOKENS 2048   // B*S
#define DDIM   1024
#define HDIM   2048
#define NEXP   8

typedef __attribute__((ext_vector_type(8))) short short8;
typedef __attribute__((ext_vector_type(4))) float f32x4;

typedef __attribute__((address_space(3))) unsigned int as3_uint;
typedef __attribute__((address_space(1))) unsigned int as1_uint;

__device__ __forceinline__ void gld16(const void* g, void* l) {
    __builtin_amdgcn_global_load_lds((const as1_uint*)g, (as3_uint*)l, 16, 0, 0);
}

__device__ __forceinline__ ushort f2bf(float f) {
    unsigned u = __float_as_uint(f);
    unsigned r = (u + 0x7fffu + ((u >> 16) & 1u)) >> 16;   // RNE
    return (ushort)r;
}

// ---------------- workspace layout (bytes) ----------------
// 0        : int cnt[8], float usage[8], float zsum, pad, int base[9]  (first 128 zeroed)
// 128      : float wtok[2048]
// 8320     : int toklist[8*2048]
// 74752    : ushort xg[4096*1024]      8,388,608 B
// 8463360  : ushort gs[4096*2048]     16,777,216 B
// 25240576 : ushort wb1 tiles         33,554,432 B  (pre-swizzled 128x64 tiles)
// 58795008 : ushort wb2 tiles         33,554,432 B
// 92349440 : ushort wb3 tiles         33,554,432 B
// end 125,903,872

// ---------------- gate (device body, shared by standalone + fused) ----------------
struct GateSmem {
    float sm[4][8];
    float zsm[4];
};

__device__ __forceinline__ void gate_block(
    int bid, GateSmem& gsm,
    const float* __restrict__ x, const float* __restrict__ Wg,
    float* __restrict__ out_scores,
    float* __restrict__ usage, float* __restrict__ zsum,
    int* __restrict__ cnt, float* __restrict__ wtok, int* __restrict__ toklist)
{
    const int lane = threadIdx.x & 63;
    const int wv   = threadIdx.x >> 6;
    const int t    = bid * 4 + wv;

    float acc[8] = {0.f,0.f,0.f,0.f,0.f,0.f,0.f,0.f};
    const float* xr = x + (size_t)t * DDIM;
    for (int d = lane; d < DDIM; d += 64) {
        float xv = xr[d];
        const float* wg = Wg + d * 8;
        #pragma unroll
        for (int e = 0; e < 8; e++) acc[e] += xv * wg[e];
    }
    #pragma unroll
    for (int off = 32; off >= 1; off >>= 1) {
        #pragma unroll
        for (int e = 0; e < 8; e++) acc[e] += __shfl_xor(acc[e], off, 64);
    }

    float mx = acc[0];
    #pragma unroll
    for (int e = 1; e < 8; e++) mx = fmaxf(mx, acc[e]);
    float s[8]; float sum = 0.f;
    #pragma unroll
    for (int e = 0; e < 8; e++) { s[e] = expf(acc[e] - mx); sum += s[e]; }
    float inv = 1.f / sum;
    #pragma unroll
    for (int e = 0; e < 8; e++) s[e] *= inv;
    float lse = mx + logf(sum);

    if (lane == 0) {
        int i0 = 0;
        #pragma unroll
        for (int e = 1; e < 8; e++) if (s[e] > s[i0]) i0 = e;
        int i1 = (i0 == 0) ? 1 : 0;
        #pragma unroll
        for (int e = 0; e < 8; e++) if (e != i0 && s[e] > s[i1]) i1 = e;

        wtok[t] = s[i0] + s[i1];
        #pragma unroll
        for (int e = 0; e < 8; e++) {
            out_scores[(size_t)t * 8 + e] = s[e];
            gsm.sm[wv][e] = s[e];
        }
        gsm.zsm[wv] = lse * lse;

        int p0 = atomicAdd(&cnt[i0], 1);
        toklist[i0 * TOKENS + p0] = t;
        int p1 = atomicAdd(&cnt[i1], 1);
        toklist[i1 * TOKENS + p1] = t;
    }
    __syncthreads();
    if (threadIdx.x < 8) {
        float u = gsm.sm[0][threadIdx.x] + gsm.sm[1][threadIdx.x] +
                  gsm.sm[2][threadIdx.x] + gsm.sm[3][threadIdx.x];
        atomicAdd(&usage[threadIdx.x], u);
    }
    if (threadIdx.x == 8) {
        atomicAdd(zsum, gsm.zsm[0] + gsm.zsm[1] + gsm.zsm[2] + gsm.zsm[3]);
    }
}

// ---------------- convert: LDS-staged (global_load_lds), 2 tiles/block ----------------
// fp32 [E][K][N] -> bf16 pre-swizzled tiles [e][nt][kt][16KB].
// gld16 keeps load data out of VGPRs -> 16 loads/wave in flight (no reg-starved
// serialization). Padded [64][257] fp32 stage kills read-back bank conflicts.
__device__ __forceinline__ void convert2_block(
    int pr, int kt, int e, float* stage /* [64][257] */,
    const float* __restrict__ src, ushort* __restrict__ dst, int N, int K)
{
    const int NT = N >> 7, KT = K >> 6;
    const int tid  = threadIdx.x;
    const int lane = tid & 63;
    const int wv   = tid >> 6;
    const int nt0  = pr * 2;
    const size_t ebase = (size_t)e * K * N;
    const float* tsrc = src + ebase + (size_t)(kt * 64) * N + nt0 * 128;

    // stage 64 rows x 256 fp32 (1KB/row) via global_load_lds
    #pragma unroll
    for (int i = 0; i < 16; i++) {
        int r = wv * 16 + i;
        gld16(tsrc + (size_t)r * N + lane * 4, (char*)stage + r * 1028);
    }
    __syncthreads();   // drains vmcnt; stage ready

    // convert + write swizzled-tile image, coalesced 1KB/wave stores
    #pragma unroll
    for (int it = 0; it < 8; it++) {
        int g    = tid + it * 256;      // 0..2047 chunks (2 tiles x 1024)
        int j2   = g >> 10;             // which tile of the pair
        int o    = (g & 1023) * 16;     // byte offset in tile
        int n    = o >> 7;
        int kblk = ((o & 127) ^ ((n & 7) << 4)) >> 4;
        union { ushort us[8]; uint4 v; } pk;
        #pragma unroll
        for (int kk = 0; kk < 8; kk++)
            pk.us[kk] = f2bf(stage[(kblk * 8 + kk) * 257 + n + j2 * 128]);
        char* tb = (char*)dst + (((size_t)(e * NT + nt0 + j2)) * KT + kt) * 16384;
        *(uint4*)(tb + o) = pk.v;
    }
}

// ---------------- fused prep: gate (512) first, then converts (3072) ----------------
__global__ __launch_bounds__(256) void prep_kernel(
    const float* __restrict__ x, const float* __restrict__ Wg,
    const float* __restrict__ W1, const float* __restrict__ W2,
    const float* __restrict__ W3,
    ushort* __restrict__ wb1, ushort* __restrict__ wb2, ushort* __restrict__ wb3,
    float* __restrict__ out_scores,
    float* __restrict__ usage, float* __restrict__ zsum,
    int* __restrict__ cnt, float* __restrict__ wtok, int* __restrict__ toklist)
{
    __shared__ union {
        GateSmem g;
        float st[64 * 257];   // 65,792 B fp32 stage
    } smu;

    const int bid = blockIdx.x;
    if (bid < 512) {                              // gate first (latency tail hidden)
        gate_block(bid, smu.g, x, Wg, out_scores, usage, zsum, cnt, wtok, toklist);
    } else if (bid < 512 + 1024) {                // W1: 8 pairs x 16 kt x 8 e
        int b = bid - 512, rem = b & 127;
        convert2_block(rem & 7, rem >> 3, b >> 7, smu.st, W1, wb1, HDIM, DDIM);
    } else if (bid < 512 + 2048) {                // W2
        int b = bid - (512 + 1024), rem = b & 127;
        convert2_block(rem & 7, rem >> 3, b >> 7, smu.st, W2, wb2, HDIM, DDIM);
    } else {                                      // W3: 4 pairs x 32 kt x 8 e
        int b = bid - (512 + 2048), rem = b & 127;
        convert2_block(rem & 3, rem >> 2, b >> 7, smu.st, W3, wb3, DDIM, HDIM);
    }
}

// standalone gate for the fallback path
__global__ __launch_bounds__(256) void gate_kernel(
    const float* __restrict__ x, const float* __restrict__ Wg,
    float* __restrict__ out_scores,
    float* __restrict__ usage, float* __restrict__ zsum,
    int* __restrict__ cnt, float* __restrict__ wtok, int* __restrict__ toklist)
{
    __shared__ GateSmem gsm;
    gate_block(blockIdx.x, gsm, x, Wg, out_scores, usage, zsum, cnt, wtok, toklist);
}

__global__ void scan_finalize_kernel(const int* __restrict__ cnt, int* __restrict__ base,
                                     const float* __restrict__ usage,
                                     const float* __restrict__ zsum,
                                     float* __restrict__ out_aux)
{
    if (threadIdx.x == 0) {
        int b = 0;
        #pragma unroll
        for (int e = 0; e < 8; e++) { base[e] = b; b += cnt[e]; }
        base[8] = b;
        float lb = 0.f;
        #pragma unroll
        for (int e = 0; e < 8; e++) {
            float u = usage[e] / (float)TOKENS;
            lb -= u * logf(u + 1e-9f);
        }
        out_aux[0] = lb + (zsum[0] / (float)TOKENS) * 1e-3f;
    }
}

// gather x rows per (expert, slot) into compacted bf16 xg[pair][1024]
__global__ __launch_bounds__(256) void gather_kernel(
    const float* __restrict__ x, const int* __restrict__ cnt,
    const int* __restrict__ base, const int* __restrict__ toklist,
    ushort* __restrict__ xg)
{
    const int e  = blockIdx.y;
    const int it = blockIdx.x;
    const int n  = cnt[e];
    const int i0 = it * 64;
    if (i0 >= n) return;

    __shared__ int rws[64];
    const int tid = threadIdx.x;
    if (tid < 64) rws[tid] = (i0 + tid < n) ? toklist[e * TOKENS + i0 + tid] : -1;
    __syncthreads();

    const int pbase = base[e] + i0;
    for (int idx = tid; idx < 64 * 256; idx += 256) {
        int r = idx >> 8, c = idx & 255;
        int t = rws[r];
        if (t < 0) continue;
        float4 v = *(const float4*)(x + (size_t)t * DDIM + c * 4);
        union { ushort us[4]; uint2 u; } pk;
        pk.us[0] = f2bf(v.x); pk.us[1] = f2bf(v.y);
        pk.us[2] = f2bf(v.z); pk.us[3] = f2bf(v.w);
        *(uint2*)(xg + (size_t)(pbase + r) * DDIM + c * 4) = pk.u;
    }
}

// ============ preconverted-weight GEMMs (R9 composition, 273us proven) ============

// GEMM1 + SwiGLU (R5-proven, 78us): 512 thr, tile 128m x 128h, BK=64, LDS 48KB
// single-buffer, reg-staged async prefetch (T14): loads for kt+1 issue before
// MFMA(kt); ds_write between the two barriers. 2 blocks/CU.
__global__ __launch_bounds__(512, 4) void gemm1_pre(
    const ushort* __restrict__ xg,
    const ushort* __restrict__ wb1, const ushort* __restrict__ wb2,
    const float* __restrict__ b1, const float* __restrict__ b2,
    const int* __restrict__ cnt, const int* __restrict__ base,
    ushort* __restrict__ gs)
{
    const int e  = blockIdx.z;
    const int mt = blockIdx.y;
    const int ht = blockIdx.x;
    const int n  = cnt[e];
    if (mt * 128 >= n) return;
    const int nrows = min(128, n - mt * 128);
    const int p0 = base[e] + mt * 128;
    const int hb = ht * 128;

    __shared__ alignas(16) char smem[49152];   // A 16K | B1 16K | B2 16K

    const int tid  = threadIdx.x;
    const int lane = tid & 63;
    const int wv   = tid >> 6;            // 0..7
    const int wm   = (wv & 1) * 64;
    const int wn   = (wv >> 1) * 32;

    f32x4 c1[4][2], c2[4][2];
    #pragma unroll
    for (int mi = 0; mi < 4; mi++)
        #pragma unroll
        for (int ni = 0; ni < 2; ni++) { c1[mi][ni] = (f32x4)0.f; c2[mi][ni] = (f32x4)0.f; }

    const char* t1 = (const char*)wb1 + (size_t)(e * 16 + ht) * (16 * 16384);
    const char* t2 = (const char*)wb2 + (size_t)(e * 16 + ht) * (16 * 16384);

    // A staging role: row ar (0..127), two 8-bf16 groups at kblk akb, akb+1
    const int ar  = tid >> 2;
    const int akb = (tid & 3) * 2;
    const ushort* agp = xg + (size_t)(p0 + ar) * DDIM + akb * 8;
    const int ao0 = ar * 128 + ((akb * 16) ^ ((ar & 7) << 4));
    const int ao1 = ar * 128 + (((akb + 1) * 16) ^ ((ar & 7) << 4));

    uint4 av0, av1, bv0, bv1, bv2, bv3;

#define G1_LOAD(kt) do {                                              \
        av0 = *(const uint4*)(agp + (kt) * 64);                       \
        av1 = *(const uint4*)(agp + (kt) * 64 + 8);                   \
        const char* _p1 = t1 + (size_t)(kt) * 16384 + tid * 16;       \
        const char* _p2 = t2 + (size_t)(kt) * 16384 + tid * 16;       \
        bv0 = *(const uint4*)(_p1);                                   \
        bv1 = *(const uint4*)(_p1 + 8192);                            \
        bv2 = *(const uint4*)(_p2);                                   \
        bv3 = *(const uint4*)(_p2 + 8192);                            \
    } while (0)

#define G1_WRITE() do {                                               \
        *(uint4*)(smem + ao0) = av0;                                  \
        *(uint4*)(smem + ao1) = av1;                                  \
        char* _d = smem + 16384 + tid * 16;                           \
        *(uint4*)(_d)                = bv0;                           \
        *(uint4*)(_d + 8192)         = bv1;                           \
        *(uint4*)(_d + 16384)        = bv2;                           \
        *(uint4*)(_d + 16384 + 8192) = bv3;                           \
    } while (0)

    G1_LOAD(0);
    G1_WRITE();
    __syncthreads();

    for (int kt = 0; kt < 16; kt++) {
        if (kt < 15) G1_LOAD(kt + 1);        // fly under MFMA below

        short8 af[4][2];
        #pragma unroll
        for (int mi = 0; mi < 4; mi++) {
            int row = wm + mi * 16 + (lane & 15);
            #pragma unroll
            for (int ks = 0; ks < 2; ks++) {
                int off = row * 128 + (((ks * 64) + ((lane >> 4) * 16)) ^ ((row & 7) << 4));
                af[mi][ks] = *(const short8*)(smem + off);
            }
        }
        #pragma unroll
        for (int ni = 0; ni < 2; ni++) {
            int h = wn + ni * 16 + (lane & 15);
            #pragma unroll
            for (int ks = 0; ks < 2; ks++) {
                int off = h * 128 + (((ks * 64) + ((lane >> 4) * 16)) ^ ((h & 7) << 4));
                short8 bv1r = *(const short8*)(smem + 16384 + off);
                short8 bv2r = *(const short8*)(smem + 32768 + off);
                #pragma unroll
                for (int mi = 0; mi < 4; mi++) {
                    c1[mi][ni] = __builtin_amdgcn_mfma_f32_16x16x32_bf16(af[mi][ks], bv1r, c1[mi][ni], 0, 0, 0);
                    c2[mi][ni] = __builtin_amdgcn_mfma_f32_16x16x32_bf16(af[mi][ks], bv2r, c2[mi][ni], 0, 0, 0);
                }
            }
        }

        if (kt < 15) {
            __syncthreads();                 // all reads of smem done
            G1_WRITE();                      // regs -> LDS (fast)
            __syncthreads();                 // visible for next iter
        }
    }
#undef G1_LOAD
#undef G1_WRITE

    // ---- epilogue: bias + silu*mul -> gs (bf16), direct scatter ----
    float b1v[2], b2v[2];
    #pragma unroll
    for (int ni = 0; ni < 2; ni++) {
        int h = hb + wn + ni * 16 + (lane & 15);
        b1v[ni] = b1[e * HDIM + h];
        b2v[ni] = b2[e * HDIM + h];
    }
    #pragma unroll
    for (int mi = 0; mi < 4; mi++) {
        #pragma unroll
        for (int ni = 0; ni < 2; ni++) {
            int h = hb + wn + ni * 16 + (lane & 15);
            #pragma unroll
            for (int r = 0; r < 4; r++) {
                int m = wm + mi * 16 + (lane >> 4) * 4 + r;
                if (m < nrows) {
                    float h1 = c1[mi][ni][r] + b1v[ni];
                    float h2 = c2[mi][ni][r] + b2v[ni];
                    float g = (h1 / (1.f + expf(-h1))) * h2;
                    gs[(size_t)(p0 + m) * HDIM + h] = f2bf(g);
                }
            }
        }
    }
}

// GEMM2 (R8-proven): 512 thr, tile 128m x 128d, split-K x2 (16 kt each),
// FULL double-buffer, ONE __syncthreads per K-step, LDS 64KB = 2 x (A16|B16).
__global__ __launch_bounds__(512, 4) void gemm2_pre(
    const ushort* __restrict__ gs,
    const ushort* __restrict__ wb3, const float* __restrict__ b3,
    const int* __restrict__ cnt, const int* __restrict__ base,
    const int* __restrict__ toklist, const float* __restrict__ wtok,
    float* __restrict__ out)
{
    const int e  = blockIdx.z >> 1;
    const int kh = blockIdx.z & 1;
    const int mt = blockIdx.y;
    const int nt = blockIdx.x;
    const int n  = cnt[e];
    if (mt * 128 >= n) return;
    const int nrows = min(128, n - mt * 128);
    const int p0 = base[e] + mt * 128;
    const int db = nt * 128;

    __shared__ alignas(16) char smem[65536];       // buf p at p*32768: A16|B16
    __shared__ int   rows[128];
    __shared__ float wr[128];

    const int tid  = threadIdx.x;
    const int lane = tid & 63;
    const int wv   = tid >> 6;
    const int wm   = (wv & 1) * 64;
    const int wn   = (wv >> 1) * 32;

    if (tid < 128) {
        int i = mt * 128 + tid;
        int t = (i < n) ? toklist[e * TOKENS + i] : -1;
        rows[tid] = t;
        wr[tid] = (t >= 0) ? wtok[t] : 0.f;
    }

    f32x4 c[4][2];
    #pragma unroll
    for (int mi = 0; mi < 4; mi++)
        #pragma unroll
        for (int ni = 0; ni < 2; ni++) c[mi][ni] = (f32x4)0.f;

    const char* t3 = (const char*)wb3 + (size_t)(e * 8 + nt) * (32 * 16384)
                   + (size_t)kh * (16 * 16384);
    const int bgo = wv * 2048 + lane * 16;
    const int bdo = wv * 2048;

    const int ar  = tid >> 2;
    const int akb = (tid & 3) * 2;
    const ushort* agp = gs + (size_t)(p0 + ar) * HDIM + kh * 1024 + akb * 8;
    const int ao0 = ar * 128 + ((akb * 16) ^ ((ar & 7) << 4));
    const int ao1 = ar * 128 + (((akb + 1) * 16) ^ ((ar & 7) << 4));

    uint4 av0, av1;

    // ---- prologue: fill buf0 with tile kt=0 ----
    av0 = *(const uint4*)(agp);
    av1 = *(const uint4*)(agp + 8);
    {
        char* d = smem + 16384 + bdo;
        gld16(t3 + bgo,        d);
        gld16(t3 + bgo + 1024, d + 1024);
    }
    *(uint4*)(smem + ao0) = av0;
    *(uint4*)(smem + ao1) = av1;
    __syncthreads();

    for (int kt = 0; kt < 16; kt++) {
        const int p = kt & 1;
        const char* Ab = smem + p * 32768;
        const char* Bb = Ab + 16384;
        char* Nb = smem + (p ^ 1) * 32768;

        if (kt < 15) {
            av0 = *(const uint4*)(agp + (kt + 1) * 64);
            av1 = *(const uint4*)(agp + (kt + 1) * 64 + 8);
            const size_t go = (size_t)(kt + 1) * 16384 + bgo;
            char* d = Nb + 16384 + bdo;
            gld16(t3 + go,        d);
            gld16(t3 + go + 1024, d + 1024);
        }

        short8 af[4][2];
        #pragma unroll
        for (int mi = 0; mi < 4; mi++) {
            int row = wm + mi * 16 + (lane & 15);
            #pragma unroll
            for (int ks = 0; ks < 2; ks++) {
                int off = row * 128 + (((ks * 64) + ((lane >> 4) * 16)) ^ ((row & 7) << 4));
                af[mi][ks] = *(const short8*)(Ab + off);
            }
        }
        #pragma unroll
        for (int ni = 0; ni < 2; ni++) {
            int d = wn + ni * 16 + (lane & 15);
            #pragma unroll
            for (int ks = 0; ks < 2; ks++) {
                int off = d * 128 + (((ks * 64) + ((lane >> 4) * 16)) ^ ((d & 7) << 4));
                short8 bv = *(const short8*)(Bb + off);
                #pragma unroll
                for (int mi = 0; mi < 4; mi++)
                    c[mi][ni] = __builtin_amdgcn_mfma_f32_16x16x32_bf16(af[mi][ks], bv, c[mi][ni], 0, 0, 0);
            }
        }

        if (kt < 15) {
            *(uint4*)(Nb + ao0) = av0;
            *(uint4*)(Nb + ao1) = av1;
        }
        __syncthreads();
    }

    float b3v[2];
    #pragma unroll
    for (int ni = 0; ni < 2; ni++)
        b3v[ni] = (kh == 0) ? b3[e * DDIM + db + wn + ni * 16 + (lane & 15)] : 0.f;

    #pragma unroll
    for (int mi = 0; mi < 4; mi++) {
        #pragma unroll
        for (int r = 0; r < 4; r++) {
            int m = wm + mi * 16 + (lane >> 4) * 4 + r;
            if (m < nrows) {
                int t = rows[m];
                float w = wr[m];
                #pragma unroll
                for (int ni = 0; ni < 2; ni++) {
                    int d = db + wn + ni * 16 + (lane & 15);
                    atomicAdd(&out[(size_t)t * DDIM + d], (c[mi][ni][r] + b3v[ni]) * w);
                }
            }
        }
    }
}

// ============ fallback (on-the-fly conversion) GEMMs — R2 versions ============

__global__ __launch_bounds__(256) void gemm1_fb(
    const ushort* __restrict__ xg,
    const float* __restrict__ W1, const float* __restrict__ b1,
    const float* __restrict__ W2, const float* __restrict__ b2,
    const int* __restrict__ cnt, const int* __restrict__ base,
    ushort* __restrict__ gs)
{
    const int e  = blockIdx.z;
    const int mt = blockIdx.y;
    const int ht = blockIdx.x;
    const int n  = cnt[e];
    if (mt * 64 >= n) return;
    const int nrows = min(64, n - mt * 64);
    const int p0 = base[e] + mt * 64;
    const int hb = ht * 128;

    __shared__ alignas(16) ushort As[64 * 64];
    __shared__ alignas(16) ushort Bs1[128 * 64];
    __shared__ alignas(16) ushort Bs2[128 * 64];

    const int tid  = threadIdx.x;
    const int lane = tid & 63;
    const int wv   = tid >> 6;
    const int wm   = (wv & 1) * 32;
    const int wn   = (wv >> 1) * 64;

    f32x4 c1[2][4], c2[2][4];
    #pragma unroll
    for (int mi = 0; mi < 2; mi++)
        #pragma unroll
        for (int ni = 0; ni < 4; ni++) { c1[mi][ni] = (f32x4)0.f; c2[mi][ni] = (f32x4)0.f; }

    const size_t ebase = (size_t)e * DDIM * HDIM;
    const int kb8 = (tid & 7) * 8;
    const int h4  = (tid >> 3) * 4;

    for (int kb = 0; kb < DDIM; kb += 64) {
        __syncthreads();
        #pragma unroll
        for (int c = 0; c < 2; c++) {
            int s = tid + c * 256;
            int m = s >> 3, kblk = s & 7;
            uint4 v = *(const uint4*)(xg + (size_t)(p0 + m) * DDIM + kb + kblk * 8);
            int off = m * 128 + ((kblk * 16) ^ ((m & 7) << 4));
            *(uint4*)((char*)As + off) = v;
        }
        {
            union { ushort us[8]; uint4 v; } t1[4], t2[4];
            #pragma unroll
            for (int kk = 0; kk < 8; kk++) {
                const size_t ro = ebase + (size_t)(kb + kb8 + kk) * HDIM + hb + h4;
                float4 w1 = *(const float4*)(W1 + ro);
                float4 w2 = *(const float4*)(W2 + ro);
                t1[0].us[kk] = f2bf(w1.x); t1[1].us[kk] = f2bf(w1.y);
                t1[2].us[kk] = f2bf(w1.z); t1[3].us[kk] = f2bf(w1.w);
                t2[0].us[kk] = f2bf(w2.x); t2[1].us[kk] = f2bf(w2.y);
                t2[2].us[kk] = f2bf(w2.z); t2[3].us[kk] = f2bf(w2.w);
            }
            #pragma unroll
            for (int i = 0; i < 4; i++) {
                int h = h4 + i;
                int off = h * 128 + ((kb8 * 2) ^ ((h & 7) << 4));
                *(uint4*)((char*)Bs1 + off) = t1[i].v;
                *(uint4*)((char*)Bs2 + off) = t2[i].v;
            }
        }
        __syncthreads();
        #pragma unroll
        for (int ks = 0; ks < 2; ks++) {
            short8 af[2];
            #pragma unroll
            for (int mi = 0; mi < 2; mi++) {
                int row = wm + mi * 16 + (lane & 15);
                int off = row * 128 + (((ks * 64) + ((lane >> 4) * 16)) ^ ((row & 7) << 4));
                af[mi] = *(const short8*)((const char*)As + off);
            }
            #pragma unroll
            for (int ni = 0; ni < 4; ni++) {
                int h = wn + ni * 16 + (lane & 15);
                int off = h * 128 + (((ks * 64) + ((lane >> 4) * 16)) ^ ((h & 7) << 4));
                short8 bf1 = *(const short8*)((const char*)Bs1 + off);
                short8 bf2 = *(const short8*)((const char*)Bs2 + off);
                #pragma unroll
                for (int mi = 0; mi < 2; mi++) {
                    c1[mi][ni] = __builtin_amdgcn_mfma_f32_16x16x32_bf16(af[mi], bf1, c1[mi][ni], 0, 0, 0);
                    c2[mi][ni] = __builtin_amdgcn_mfma_f32_16x16x32_bf16(af[mi], bf2, c2[mi][ni], 0, 0, 0);
                }
            }
        }
    }

    float b1v[4], b2v[4];
    #pragma unroll
    for (int ni = 0; ni < 4; ni++) {
        int h = hb + wn + ni * 16 + (lane & 15);
        b1v[ni] = b1[e * HDIM + h];
        b2v[ni] = b2[e * HDIM + h];
    }
    #pragma unroll
    for (int mi = 0; mi < 2; mi++) {
        #pragma unroll
        for (int ni = 0; ni < 4; ni++) {
            int h = hb + wn + ni * 16 + (lane & 15);
            #pragma unroll
            for (int r = 0; r < 4; r++) {
                int m = wm + mi * 16 + (lane >> 4) * 4 + r;
                if (m < nrows) {
                    float h1 = c1[mi][ni][r] + b1v[ni];
                    float h2 = c2[mi][ni][r] + b2v[ni];
                    float g = (h1 / (1.f + expf(-h1))) * h2;
                    gs[(size_t)(p0 + m) * HDIM + h] = f2bf(g);
                }
            }
        }
    }
}

__global__ __launch_bounds__(256) void gemm2_fb(
    const ushort* __restrict__ gs,
    const float* __restrict__ W3, const float* __restrict__ b3,
    const int* __restrict__ cnt, const int* __restrict__ base,
    const int* __restrict__ toklist, const float* __restrict__ wtok,
    float* __restrict__ out)
{
    const int e  = blockIdx.z;
    const int mt = blockIdx.y;
    const int nt = blockIdx.x;
    const int n  = cnt[e];
    if (mt * 64 >= n) return;
    const int nrows = min(64, n - mt * 64);
    const int p0 = base[e] + mt * 64;
    const int db = nt * 256;

    __shared__ alignas(16) ushort As[64 * 64];
    __shared__ alignas(16) ushort Bs[256 * 64];
    __shared__ int   rows[64];
    __shared__ float wr[64];

    const int tid  = threadIdx.x;
    const int lane = tid & 63;
    const int wv   = tid >> 6;
    const int wm   = (wv & 1) * 32;
    const int wn   = (wv >> 1) * 128;

    if (tid < 64) {
        int i = mt * 64 + tid;
        int t = (i < n) ? toklist[e * TOKENS + i] : -1;
        rows[tid] = t;
        wr[tid] = (t >= 0) ? wtok[t] : 0.f;
    }

    f32x4 c[2][8];
    #pragma unroll
    for (int mi = 0; mi < 2; mi++)
        #pragma unroll
        for (int ni = 0; ni < 8; ni++) c[mi][ni] = (f32x4)0.f;

    const size_t ebase = (size_t)e * HDIM * DDIM;

    for (int kb = 0; kb < HDIM; kb += 64) {
        __syncthreads();
        #pragma unroll
        for (int cc = 0; cc < 2; cc++) {
            int s = tid + cc * 256;
            int m = s >> 3, kblk = s & 7;
            uint4 v = *(const uint4*)(gs + (size_t)(p0 + m) * HDIM + kb + kblk * 8);
            int off = m * 128 + ((kblk * 16) ^ ((m & 7) << 4));
            *(uint4*)((char*)As + off) = v;
        }
        #pragma unroll
        for (int ss = 0; ss < 2; ss++) {
            int s = tid + ss * 256;
            int kb8 = (s & 7) * 8;
            int d4  = (s >> 3) * 4;
            union { ushort us[8]; uint4 v; } t3[4];
            #pragma unroll
            for (int kk = 0; kk < 8; kk++) {
                float4 w = *(const float4*)(W3 + ebase + (size_t)(kb + kb8 + kk) * DDIM + db + d4);
                t3[0].us[kk] = f2bf(w.x); t3[1].us[kk] = f2bf(w.y);
                t3[2].us[kk] = f2bf(w.z); t3[3].us[kk] = f2bf(w.w);
            }
            #pragma unroll
            for (int i = 0; i < 4; i++) {
                int d = d4 + i;
                int off = d * 128 + ((kb8 * 2) ^ ((d & 7) << 4));
                *(uint4*)((char*)Bs + off) = t3[i].v;
            }
        }
        __syncthreads();
        #pragma unroll
        for (int ks = 0; ks < 2; ks++) {
            short8 af[2];
            #pragma unroll
            for (int mi = 0; mi < 2; mi++) {
                int row = wm + mi * 16 + (lane & 15);
                int off = row * 128 + (((ks * 64) + ((lane >> 4) * 16)) ^ ((row & 7) << 4));
                af[mi] = *(const short8*)((const char*)As + off);
            }
            #pragma unroll
            for (int ni = 0; ni < 8; ni++) {
                int d = wn + ni * 16 + (lane & 15);
                int off = d * 128 + (((ks * 64) + ((lane >> 4) * 16)) ^ ((d & 7) << 4));
                short8 bf = *(const short8*)((const char*)Bs + off);
                #pragma unroll
                for (int mi = 0; mi < 2; mi++)
                    c[mi][ni] = __builtin_amdgcn_mfma_f32_16x16x32_bf16(af[mi], bf, c[mi][ni], 0, 0, 0);
            }
        }
    }

    float b3v[8];
    #pragma unroll
    for (int ni = 0; ni < 8; ni++)
        b3v[ni] = b3[e * DDIM + db + wn + ni * 16 + (lane & 15)];

    #pragma unroll
    for (int mi = 0; mi < 2; mi++) {
        #pragma unroll
        for (int r = 0; r < 4; r++) {
            int m = wm + mi * 16 + (lane >> 4) * 4 + r;
            if (m < nrows) {
                int t = rows[m];
                float w = wr[m];
                #pragma unroll
                for (int ni = 0; ni < 8; ni++) {
                    int d = db + wn + ni * 16 + (lane & 15);
                    atomicAdd(&out[(size_t)t * DDIM + d], (c[mi][ni][r] + b3v[ni]) * w);
                }
            }
        }
    }
}

extern "C" void kernel_launch(void* const* d_in, const int* in_sizes, int n_in,
                              void* d_out, int out_size, void* d_ws, size_t ws_size,
                              hipStream_t stream) {
    const float* x  = (const float*)d_in[0];
    const float* Wg = (const float*)d_in[1];
    const float* W1 = (const float*)d_in[2];
    const float* b1 = (const float*)d_in[3];
    const float* W2 = (const float*)d_in[4];
    const float* b2 = (const float*)d_in[5];
    const float* W3 = (const float*)d_in[6];
    const float* b3 = (const float*)d_in[7];

    float* out        = (float*)d_out;
    float* out_aux    = out + (size_t)TOKENS * DDIM;
    float* out_scores = out_aux + 1;

    int*   cnt     = (int*)d_ws;
    float* usage   = (float*)d_ws + 8;
    float* zsum    = (float*)d_ws + 16;
    int*   basep   = (int*)d_ws + 20;
    float* wtok    = (float*)d_ws + 32;
    int*   toklist = (int*)d_ws + 32 + TOKENS;
    ushort* xg     = (ushort*)((char*)d_ws + 74752);
    ushort* gsbuf  = (ushort*)((char*)d_ws + 8463360);
    ushort* wb1    = (ushort*)((char*)d_ws + 25240576);
    ushort* wb2    = (ushort*)((char*)d_ws + 58795008);
    ushort* wb3    = (ushort*)((char*)d_ws + 92349440);

    const bool pre = ws_size >= 125903872ull;

    hipMemsetAsync(d_ws, 0, 128, stream);
    hipMemsetAsync(d_out, 0, (size_t)out_size * sizeof(float), stream);

    if (pre) {
        // fused: 512 gate blocks first, then 3072 convert blocks (2 tiles each,
        // LDS-staged via global_load_lds)
        prep_kernel<<<512 + 3072, 256, 0, stream>>>(
            x, Wg, W1, W2, W3, wb1, wb2, wb3,
            out_scores, usage, zsum, cnt, wtok, toklist);
        scan_finalize_kernel<<<1, 64, 0, stream>>>(cnt, basep, usage, zsum, out_aux);

        dim3 gg(32, NEXP);
        gather_kernel<<<gg, 256, 0, stream>>>(x, cnt, basep, toklist, xg);

        dim3 g1(HDIM / 128, 16, NEXP);
        gemm1_pre<<<g1, 512, 0, stream>>>(xg, wb1, wb2, b1, b2, cnt, basep, gsbuf);

        dim3 g2(DDIM / 128, 16, NEXP * 2);
        gemm2_pre<<<g2, 512, 0, stream>>>(gsbuf, wb3, b3, cnt, basep, toklist, wtok, out);
    } else {
        gate_kernel<<<TOKENS / 4, 256, 0, stream>>>(x, Wg, out_scores, usage, zsum,
                                                    cnt, wtok, toklist);
        scan_finalize_kernel<<<1, 64, 0, stream>>>(cnt, basep, usage, zsum, out_aux);

        dim3 gg(32, NEXP);
        gather_kernel<<<gg, 256, 0, stream>>>(x, cnt, basep, toklist, xg);

        dim3 g1(HDIM / 128, TOKENS / 64, NEXP);
        gemm1_fb<<<g1, 256, 0, stream>>>(xg, W1, b1, W2, b2, cnt, basep, gsbuf);

        dim3 g2(DDIM / 256, TOKENS / 64, NEXP);
        gemm2_fb<<<g2, 256, 0, stream>>>(gsbuf, W3, b3, cnt, basep, toklist, wtok, out);
    }
}

// Round 14
// 262.814 us; speedup vs baseline: 1.0564x; 1.0564x over previous
//
#include <hip/hip_runtime.h>
#include <hip/hip_bf16.h>
#include <math.h>

#define TOKENS 2048   // B*S
#define DDIM   1024
#define HDIM   2048
#define NEXP   8

typedef __attribute__((ext_vector_type(8))) short short8;
typedef __attribute__((ext_vector_type(4))) float f32x4;

typedef __attribute__((address_space(3))) unsigned int as3_uint;
typedef __attribute__((address_space(1))) unsigned int as1_uint;

__device__ __forceinline__ void gld16(const void* g, void* l) {
    __builtin_amdgcn_global_load_lds((const as1_uint*)g, (as3_uint*)l, 16, 0, 0);
}

__device__ __forceinline__ ushort f2bf(float f) {
    unsigned u = __float_as_uint(f);
    unsigned r = (u + 0x7fffu + ((u >> 16) & 1u)) >> 16;   // RNE
    return (ushort)r;
}

// ---------------- workspace layout (bytes) ----------------
// 0        : int cnt[8], float usage[8], float zsum, pad, int base[9]  (first 128 zeroed)
// 128      : float wtok[2048]
// 8320     : int toklist[8*2048]
// 74752    : ushort xg[4096*1024]      8,388,608 B
// 8463360  : ushort gs[4096*2048]     16,777,216 B
// 25240576 : ushort wb1 tiles         33,554,432 B  (pre-swizzled 128x64 tiles)
// 58795008 : ushort wb2 tiles         33,554,432 B
// 92349440 : ushort wb3 tiles         33,554,432 B
// end 125,903,872

// ---------------- gate (device body, shared by standalone + fused) ----------------
struct GateSmem {
    float sm[4][8];
    float zsm[4];
};

__device__ __forceinline__ void gate_block(
    int bid, GateSmem& gsm,
    const float* __restrict__ x, const float* __restrict__ Wg,
    float* __restrict__ out_scores,
    float* __restrict__ usage, float* __restrict__ zsum,
    int* __restrict__ cnt, float* __restrict__ wtok, int* __restrict__ toklist)
{
    const int lane = threadIdx.x & 63;
    const int wv   = threadIdx.x >> 6;
    const int t    = bid * 4 + wv;

    float acc[8] = {0.f,0.f,0.f,0.f,0.f,0.f,0.f,0.f};
    const float* xr = x + (size_t)t * DDIM;
    for (int d = lane; d < DDIM; d += 64) {
        float xv = xr[d];
        const float* wg = Wg + d * 8;
        #pragma unroll
        for (int e = 0; e < 8; e++) acc[e] += xv * wg[e];
    }
    #pragma unroll
    for (int off = 32; off >= 1; off >>= 1) {
        #pragma unroll
        for (int e = 0; e < 8; e++) acc[e] += __shfl_xor(acc[e], off, 64);
    }

    float mx = acc[0];
    #pragma unroll
    for (int e = 1; e < 8; e++) mx = fmaxf(mx, acc[e]);
    float s[8]; float sum = 0.f;
    #pragma unroll
    for (int e = 0; e < 8; e++) { s[e] = expf(acc[e] - mx); sum += s[e]; }
    float inv = 1.f / sum;
    #pragma unroll
    for (int e = 0; e < 8; e++) s[e] *= inv;
    float lse = mx + logf(sum);

    if (lane == 0) {
        int i0 = 0;
        #pragma unroll
        for (int e = 1; e < 8; e++) if (s[e] > s[i0]) i0 = e;
        int i1 = (i0 == 0) ? 1 : 0;
        #pragma unroll
        for (int e = 0; e < 8; e++) if (e != i0 && s[e] > s[i1]) i1 = e;

        wtok[t] = s[i0] + s[i1];
        #pragma unroll
        for (int e = 0; e < 8; e++) {
            out_scores[(size_t)t * 8 + e] = s[e];
            gsm.sm[wv][e] = s[e];
        }
        gsm.zsm[wv] = lse * lse;

        int p0 = atomicAdd(&cnt[i0], 1);
        toklist[i0 * TOKENS + p0] = t;
        int p1 = atomicAdd(&cnt[i1], 1);
        toklist[i1 * TOKENS + p1] = t;
    }
    __syncthreads();
    if (threadIdx.x < 8) {
        float u = gsm.sm[0][threadIdx.x] + gsm.sm[1][threadIdx.x] +
                  gsm.sm[2][threadIdx.x] + gsm.sm[3][threadIdx.x];
        atomicAdd(&usage[threadIdx.x], u);
    }
    if (threadIdx.x == 8) {
        atomicAdd(zsum, gsm.zsm[0] + gsm.zsm[1] + gsm.zsm[2] + gsm.zsm[3]);
    }
}

// ---------------- convert: 2 adjacent nt tiles (R12 body, reg-staged) ----------------
// fp32 [E][K][N] -> bf16 pre-swizzled tiles [e][nt][kt][16KB].
__device__ __forceinline__ void convert2_block(
    int pr, int kt, int e, ushort* Ls,
    const float* __restrict__ src, ushort* __restrict__ dst, int N, int K)
{
    const int NT = N >> 7, KT = K >> 6;
    const int tid = threadIdx.x;
    const int kb8 = (tid & 7) * 8;
    const int n4  = (tid >> 3) * 4;
    const size_t ebase = (size_t)e * K * N;
    const int nt0 = pr * 2;

    float4 w0[8], w1[8];
    const float* rbase = src + ebase + (size_t)(kt * 64 + kb8) * N + nt0 * 128 + n4;
    #pragma unroll
    for (int kk = 0; kk < 8; kk++) {
        w0[kk] = *(const float4*)(rbase + (size_t)kk * N);
        w1[kk] = *(const float4*)(rbase + (size_t)kk * N + 128);
    }

    union { ushort us[8]; uint4 v; } t0[4], t1[4];
    #pragma unroll
    for (int kk = 0; kk < 8; kk++) {
        t0[0].us[kk] = f2bf(w0[kk].x); t0[1].us[kk] = f2bf(w0[kk].y);
        t0[2].us[kk] = f2bf(w0[kk].z); t0[3].us[kk] = f2bf(w0[kk].w);
        t1[0].us[kk] = f2bf(w1[kk].x); t1[1].us[kk] = f2bf(w1[kk].y);
        t1[2].us[kk] = f2bf(w1[kk].z); t1[3].us[kk] = f2bf(w1[kk].w);
    }
    #pragma unroll
    for (int i = 0; i < 4; i++) {
        int n = n4 + i;
        int off = n * 128 + ((kb8 * 2) ^ ((n & 7) << 4));
        *(uint4*)((char*)Ls + off) = t0[i].v;
        *(uint4*)((char*)Ls + 16384 + off) = t1[i].v;
    }
    __syncthreads();

    #pragma unroll
    for (int j2 = 0; j2 < 2; j2++) {
        char* tb = (char*)dst + (((size_t)(e * NT + nt0 + j2)) * KT + kt) * 16384;
        const char* lsrc = (const char*)Ls + j2 * 16384;
        #pragma unroll
        for (int j = 0; j < 4; j++)
            *(uint4*)(tb + j * 4096 + tid * 16) = *(const uint4*)(lsrc + j * 4096 + tid * 16);
    }
}

// ---------------- fused prep: gate (512) + page-local converts (1024) ----------------
// Each convert block owns a 4KB-per-row span (W1/W2: 4 pairs; W3: 2 pairs),
// iterated serially -> HBM pages consumed in 4KB runs instead of 1KB.
__global__ __launch_bounds__(256) void prep_kernel(
    const float* __restrict__ x, const float* __restrict__ Wg,
    const float* __restrict__ W1, const float* __restrict__ W2,
    const float* __restrict__ W3,
    ushort* __restrict__ wb1, ushort* __restrict__ wb2, ushort* __restrict__ wb3,
    float* __restrict__ out_scores,
    float* __restrict__ usage, float* __restrict__ zsum,
    int* __restrict__ cnt, float* __restrict__ wtok, int* __restrict__ toklist)
{
    __shared__ union {
        GateSmem g;
        ushort Ls[16384];   // 32KB: two tiles
    } smu;

    const int bid = blockIdx.x;
    if (bid < 512) {                              // gate first (latency tail hidden)
        gate_block(bid, smu.g, x, Wg, out_scores, usage, zsum, cnt, wtok, toklist);
    } else if (bid < 512 + 256) {                 // W1: 2 halves x 16 kt x 8 e
        int b = bid - 512;
        int half = b & 1, kt = (b >> 1) & 15, e = b >> 5;
        #pragma unroll 1
        for (int p = 0; p < 4; p++) {
            convert2_block(half * 4 + p, kt, e, smu.Ls, W1, wb1, HDIM, DDIM);
            __syncthreads();
        }
    } else if (bid < 512 + 512) {                 // W2
        int b = bid - (512 + 256);
        int half = b & 1, kt = (b >> 1) & 15, e = b >> 5;
        #pragma unroll 1
        for (int p = 0; p < 4; p++) {
            convert2_block(half * 4 + p, kt, e, smu.Ls, W2, wb2, HDIM, DDIM);
            __syncthreads();
        }
    } else {                                      // W3: 2 halves x 32 kt x 8 e
        int b = bid - (512 + 512);
        int half = b & 1, kt = (b >> 1) & 31, e = b >> 6;
        #pragma unroll 1
        for (int p = 0; p < 2; p++) {
            convert2_block(half * 2 + p, kt, e, smu.Ls, W3, wb3, DDIM, HDIM);
            __syncthreads();
        }
    }
}

// standalone gate for the fallback path
__global__ __launch_bounds__(256) void gate_kernel(
    const float* __restrict__ x, const float* __restrict__ Wg,
    float* __restrict__ out_scores,
    float* __restrict__ usage, float* __restrict__ zsum,
    int* __restrict__ cnt, float* __restrict__ wtok, int* __restrict__ toklist)
{
    __shared__ GateSmem gsm;
    gate_block(blockIdx.x, gsm, x, Wg, out_scores, usage, zsum, cnt, wtok, toklist);
}

__global__ void scan_finalize_kernel(const int* __restrict__ cnt, int* __restrict__ base,
                                     const float* __restrict__ usage,
                                     const float* __restrict__ zsum,
                                     float* __restrict__ out_aux)
{
    if (threadIdx.x == 0) {
        int b = 0;
        #pragma unroll
        for (int e = 0; e < 8; e++) { base[e] = b; b += cnt[e]; }
        base[8] = b;
        float lb = 0.f;
        #pragma unroll
        for (int e = 0; e < 8; e++) {
            float u = usage[e] / (float)TOKENS;
            lb -= u * logf(u + 1e-9f);
        }
        out_aux[0] = lb + (zsum[0] / (float)TOKENS) * 1e-3f;
    }
}

// gather x rows per (expert, slot) into compacted bf16 xg[pair][1024]
__global__ __launch_bounds__(256) void gather_kernel(
    const float* __restrict__ x, const int* __restrict__ cnt,
    const int* __restrict__ base, const int* __restrict__ toklist,
    ushort* __restrict__ xg)
{
    const int e  = blockIdx.y;
    const int it = blockIdx.x;
    const int n  = cnt[e];
    const int i0 = it * 64;
    if (i0 >= n) return;

    __shared__ int rws[64];
    const int tid = threadIdx.x;
    if (tid < 64) rws[tid] = (i0 + tid < n) ? toklist[e * TOKENS + i0 + tid] : -1;
    __syncthreads();

    const int pbase = base[e] + i0;
    for (int idx = tid; idx < 64 * 256; idx += 256) {
        int r = idx >> 8, c = idx & 255;
        int t = rws[r];
        if (t < 0) continue;
        float4 v = *(const float4*)(x + (size_t)t * DDIM + c * 4);
        union { ushort us[4]; uint2 u; } pk;
        pk.us[0] = f2bf(v.x); pk.us[1] = f2bf(v.y);
        pk.us[2] = f2bf(v.z); pk.us[3] = f2bf(v.w);
        *(uint2*)(xg + (size_t)(pbase + r) * DDIM + c * 4) = pk.u;
    }
}

// ============ preconverted-weight GEMMs (R9 composition, 273us proven) ============

// GEMM1 + SwiGLU (R5-proven, 78us): 512 thr, tile 128m x 128h, BK=64, LDS 48KB
// single-buffer, reg-staged async prefetch (T14): loads for kt+1 issue before
// MFMA(kt); ds_write between the two barriers. 2 blocks/CU.
__global__ __launch_bounds__(512, 4) void gemm1_pre(
    const ushort* __restrict__ xg,
    const ushort* __restrict__ wb1, const ushort* __restrict__ wb2,
    const float* __restrict__ b1, const float* __restrict__ b2,
    const int* __restrict__ cnt, const int* __restrict__ base,
    ushort* __restrict__ gs)
{
    const int e  = blockIdx.z;
    const int mt = blockIdx.y;
    const int ht = blockIdx.x;
    const int n  = cnt[e];
    if (mt * 128 >= n) return;
    const int nrows = min(128, n - mt * 128);
    const int p0 = base[e] + mt * 128;
    const int hb = ht * 128;

    __shared__ alignas(16) char smem[49152];   // A 16K | B1 16K | B2 16K

    const int tid  = threadIdx.x;
    const int lane = tid & 63;
    const int wv   = tid >> 6;            // 0..7
    const int wm   = (wv & 1) * 64;
    const int wn   = (wv >> 1) * 32;

    f32x4 c1[4][2], c2[4][2];
    #pragma unroll
    for (int mi = 0; mi < 4; mi++)
        #pragma unroll
        for (int ni = 0; ni < 2; ni++) { c1[mi][ni] = (f32x4)0.f; c2[mi][ni] = (f32x4)0.f; }

    const char* t1 = (const char*)wb1 + (size_t)(e * 16 + ht) * (16 * 16384);
    const char* t2 = (const char*)wb2 + (size_t)(e * 16 + ht) * (16 * 16384);

    // A staging role: row ar (0..127), two 8-bf16 groups at kblk akb, akb+1
    const int ar  = tid >> 2;
    const int akb = (tid & 3) * 2;
    const ushort* agp = xg + (size_t)(p0 + ar) * DDIM + akb * 8;
    const int ao0 = ar * 128 + ((akb * 16) ^ ((ar & 7) << 4));
    const int ao1 = ar * 128 + (((akb + 1) * 16) ^ ((ar & 7) << 4));

    uint4 av0, av1, bv0, bv1, bv2, bv3;

#define G1_LOAD(kt) do {                                              \
        av0 = *(const uint4*)(agp + (kt) * 64);                       \
        av1 = *(const uint4*)(agp + (kt) * 64 + 8);                   \
        const char* _p1 = t1 + (size_t)(kt) * 16384 + tid * 16;       \
        const char* _p2 = t2 + (size_t)(kt) * 16384 + tid * 16;       \
        bv0 = *(const uint4*)(_p1);                                   \
        bv1 = *(const uint4*)(_p1 + 8192);                            \
        bv2 = *(const uint4*)(_p2);                                   \
        bv3 = *(const uint4*)(_p2 + 8192);                            \
    } while (0)

#define G1_WRITE() do {                                               \
        *(uint4*)(smem + ao0) = av0;                                  \
        *(uint4*)(smem + ao1) = av1;                                  \
        char* _d = smem + 16384 + tid * 16;                           \
        *(uint4*)(_d)                = bv0;                           \
        *(uint4*)(_d + 8192)         = bv1;                           \
        *(uint4*)(_d + 16384)        = bv2;                           \
        *(uint4*)(_d + 16384 + 8192) = bv3;                           \
    } while (0)

    G1_LOAD(0);
    G1_WRITE();
    __syncthreads();

    for (int kt = 0; kt < 16; kt++) {
        if (kt < 15) G1_LOAD(kt + 1);        // fly under MFMA below

        short8 af[4][2];
        #pragma unroll
        for (int mi = 0; mi < 4; mi++) {
            int row = wm + mi * 16 + (lane & 15);
            #pragma unroll
            for (int ks = 0; ks < 2; ks++) {
                int off = row * 128 + (((ks * 64) + ((lane >> 4) * 16)) ^ ((row & 7) << 4));
                af[mi][ks] = *(const short8*)(smem + off);
            }
        }
        #pragma unroll
        for (int ni = 0; ni < 2; ni++) {
            int h = wn + ni * 16 + (lane & 15);
            #pragma unroll
            for (int ks = 0; ks < 2; ks++) {
                int off = h * 128 + (((ks * 64) + ((lane >> 4) * 16)) ^ ((h & 7) << 4));
                short8 bv1r = *(const short8*)(smem + 16384 + off);
                short8 bv2r = *(const short8*)(smem + 32768 + off);
                #pragma unroll
                for (int mi = 0; mi < 4; mi++) {
                    c1[mi][ni] = __builtin_amdgcn_mfma_f32_16x16x32_bf16(af[mi][ks], bv1r, c1[mi][ni], 0, 0, 0);
                    c2[mi][ni] = __builtin_amdgcn_mfma_f32_16x16x32_bf16(af[mi][ks], bv2r, c2[mi][ni], 0, 0, 0);
                }
            }
        }

        if (kt < 15) {
            __syncthreads();                 // all reads of smem done
            G1_WRITE();                      // regs -> LDS (fast)
            __syncthreads();                 // visible for next iter
        }
    }
#undef G1_LOAD
#undef G1_WRITE

    // ---- epilogue: bias + silu*mul -> gs (bf16), direct scatter ----
    float b1v[2], b2v[2];
    #pragma unroll
    for (int ni = 0; ni < 2; ni++) {
        int h = hb + wn + ni * 16 + (lane & 15);
        b1v[ni] = b1[e * HDIM + h];
        b2v[ni] = b2[e * HDIM + h];
    }
    #pragma unroll
    for (int mi = 0; mi < 4; mi++) {
        #pragma unroll
        for (int ni = 0; ni < 2; ni++) {
            int h = hb + wn + ni * 16 + (lane & 15);
            #pragma unroll
            for (int r = 0; r < 4; r++) {
                int m = wm + mi * 16 + (lane >> 4) * 4 + r;
                if (m < nrows) {
                    float h1 = c1[mi][ni][r] + b1v[ni];
                    float h2 = c2[mi][ni][r] + b2v[ni];
                    float g = (h1 / (1.f + expf(-h1))) * h2;
                    gs[(size_t)(p0 + m) * HDIM + h] = f2bf(g);
                }
            }
        }
    }
}

// GEMM2 (R8-proven): 512 thr, tile 128m x 128d, split-K x2 (16 kt each),
// FULL double-buffer, ONE __syncthreads per K-step, LDS 64KB = 2 x (A16|B16).
__global__ __launch_bounds__(512, 4) void gemm2_pre(
    const ushort* __restrict__ gs,
    const ushort* __restrict__ wb3, const float* __restrict__ b3,
    const int* __restrict__ cnt, const int* __restrict__ base,
    const int* __restrict__ toklist, const float* __restrict__ wtok,
    float* __restrict__ out)
{
    const int e  = blockIdx.z >> 1;
    const int kh = blockIdx.z & 1;
    const int mt = blockIdx.y;
    const int nt = blockIdx.x;
    const int n  = cnt[e];
    if (mt * 128 >= n) return;
    const int nrows = min(128, n - mt * 128);
    const int p0 = base[e] + mt * 128;
    const int db = nt * 128;

    __shared__ alignas(16) char smem[65536];       // buf p at p*32768: A16|B16
    __shared__ int   rows[128];
    __shared__ float wr[128];

    const int tid  = threadIdx.x;
    const int lane = tid & 63;
    const int wv   = tid >> 6;
    const int wm   = (wv & 1) * 64;
    const int wn   = (wv >> 1) * 32;

    if (tid < 128) {
        int i = mt * 128 + tid;
        int t = (i < n) ? toklist[e * TOKENS + i] : -1;
        rows[tid] = t;
        wr[tid] = (t >= 0) ? wtok[t] : 0.f;
    }

    f32x4 c[4][2];
    #pragma unroll
    for (int mi = 0; mi < 4; mi++)
        #pragma unroll
        for (int ni = 0; ni < 2; ni++) c[mi][ni] = (f32x4)0.f;

    const char* t3 = (const char*)wb3 + (size_t)(e * 8 + nt) * (32 * 16384)
                   + (size_t)kh * (16 * 16384);
    const int bgo = wv * 2048 + lane * 16;
    const int bdo = wv * 2048;

    const int ar  = tid >> 2;
    const int akb = (tid & 3) * 2;
    const ushort* agp = gs + (size_t)(p0 + ar) * HDIM + kh * 1024 + akb * 8;
    const int ao0 = ar * 128 + ((akb * 16) ^ ((ar & 7) << 4));
    const int ao1 = ar * 128 + (((akb + 1) * 16) ^ ((ar & 7) << 4));

    uint4 av0, av1;

    // ---- prologue: fill buf0 with tile kt=0 ----
    av0 = *(const uint4*)(agp);
    av1 = *(const uint4*)(agp + 8);
    {
        char* d = smem + 16384 + bdo;
        gld16(t3 + bgo,        d);
        gld16(t3 + bgo + 1024, d + 1024);
    }
    *(uint4*)(smem + ao0) = av0;
    *(uint4*)(smem + ao1) = av1;
    __syncthreads();

    for (int kt = 0; kt < 16; kt++) {
        const int p = kt & 1;
        const char* Ab = smem + p * 32768;
        const char* Bb = Ab + 16384;
        char* Nb = smem + (p ^ 1) * 32768;

        if (kt < 15) {
            av0 = *(const uint4*)(agp + (kt + 1) * 64);
            av1 = *(const uint4*)(agp + (kt + 1) * 64 + 8);
            const size_t go = (size_t)(kt + 1) * 16384 + bgo;
            char* d = Nb + 16384 + bdo;
            gld16(t3 + go,        d);
            gld16(t3 + go + 1024, d + 1024);
        }

        short8 af[4][2];
        #pragma unroll
        for (int mi = 0; mi < 4; mi++) {
            int row = wm + mi * 16 + (lane & 15);
            #pragma unroll
            for (int ks = 0; ks < 2; ks++) {
                int off = row * 128 + (((ks * 64) + ((lane >> 4) * 16)) ^ ((row & 7) << 4));
                af[mi][ks] = *(const short8*)(Ab + off);
            }
        }
        #pragma unroll
        for (int ni = 0; ni < 2; ni++) {
            int d = wn + ni * 16 + (lane & 15);
            #pragma unroll
            for (int ks = 0; ks < 2; ks++) {
                int off = d * 128 + (((ks * 64) + ((lane >> 4) * 16)) ^ ((d & 7) << 4));
                short8 bv = *(const short8*)(Bb + off);
                #pragma unroll
                for (int mi = 0; mi < 4; mi++)
                    c[mi][ni] = __builtin_amdgcn_mfma_f32_16x16x32_bf16(af[mi][ks], bv, c[mi][ni], 0, 0, 0);
            }
        }

        if (kt < 15) {
            *(uint4*)(Nb + ao0) = av0;
            *(uint4*)(Nb + ao1) = av1;
        }
        __syncthreads();
    }

    float b3v[2];
    #pragma unroll
    for (int ni = 0; ni < 2; ni++)
        b3v[ni] = (kh == 0) ? b3[e * DDIM + db + wn + ni * 16 + (lane & 15)] : 0.f;

    #pragma unroll
    for (int mi = 0; mi < 4; mi++) {
        #pragma unroll
        for (int r = 0; r < 4; r++) {
            int m = wm + mi * 16 + (lane >> 4) * 4 + r;
            if (m < nrows) {
                int t = rows[m];
                float w = wr[m];
                #pragma unroll
                for (int ni = 0; ni < 2; ni++) {
                    int d = db + wn + ni * 16 + (lane & 15);
                    atomicAdd(&out[(size_t)t * DDIM + d], (c[mi][ni][r] + b3v[ni]) * w);
                }
            }
        }
    }
}

// ============ fallback (on-the-fly conversion) GEMMs — R2 versions ============

__global__ __launch_bounds__(256) void gemm1_fb(
    const ushort* __restrict__ xg,
    const float* __restrict__ W1, const float* __restrict__ b1,
    const float* __restrict__ W2, const float* __restrict__ b2,
    const int* __restrict__ cnt, const int* __restrict__ base,
    ushort* __restrict__ gs)
{
    const int e  = blockIdx.z;
    const int mt = blockIdx.y;
    const int ht = blockIdx.x;
    const int n  = cnt[e];
    if (mt * 64 >= n) return;
    const int nrows = min(64, n - mt * 64);
    const int p0 = base[e] + mt * 64;
    const int hb = ht * 128;

    __shared__ alignas(16) ushort As[64 * 64];
    __shared__ alignas(16) ushort Bs1[128 * 64];
    __shared__ alignas(16) ushort Bs2[128 * 64];

    const int tid  = threadIdx.x;
    const int lane = tid & 63;
    const int wv   = tid >> 6;
    const int wm   = (wv & 1) * 32;
    const int wn   = (wv >> 1) * 64;

    f32x4 c1[2][4], c2[2][4];
    #pragma unroll
    for (int mi = 0; mi < 2; mi++)
        #pragma unroll
        for (int ni = 0; ni < 4; ni++) { c1[mi][ni] = (f32x4)0.f; c2[mi][ni] = (f32x4)0.f; }

    const size_t ebase = (size_t)e * DDIM * HDIM;
    const int kb8 = (tid & 7) * 8;
    const int h4  = (tid >> 3) * 4;

    for (int kb = 0; kb < DDIM; kb += 64) {
        __syncthreads();
        #pragma unroll
        for (int c = 0; c < 2; c++) {
            int s = tid + c * 256;
            int m = s >> 3, kblk = s & 7;
            uint4 v = *(const uint4*)(xg + (size_t)(p0 + m) * DDIM + kb + kblk * 8);
            int off = m * 128 + ((kblk * 16) ^ ((m & 7) << 4));
            *(uint4*)((char*)As + off) = v;
        }
        {
            union { ushort us[8]; uint4 v; } t1[4], t2[4];
            #pragma unroll
            for (int kk = 0; kk < 8; kk++) {
                const size_t ro = ebase + (size_t)(kb + kb8 + kk) * HDIM + hb + h4;
                float4 w1 = *(const float4*)(W1 + ro);
                float4 w2 = *(const float4*)(W2 + ro);
                t1[0].us[kk] = f2bf(w1.x); t1[1].us[kk] = f2bf(w1.y);
                t1[2].us[kk] = f2bf(w1.z); t1[3].us[kk] = f2bf(w1.w);
                t2[0].us[kk] = f2bf(w2.x); t2[1].us[kk] = f2bf(w2.y);
                t2[2].us[kk] = f2bf(w2.z); t2[3].us[kk] = f2bf(w2.w);
            }
            #pragma unroll
            for (int i = 0; i < 4; i++) {
                int h = h4 + i;
                int off = h * 128 + ((kb8 * 2) ^ ((h & 7) << 4));
                *(uint4*)((char*)Bs1 + off) = t1[i].v;
                *(uint4*)((char*)Bs2 + off) = t2[i].v;
            }
        }
        __syncthreads();
        #pragma unroll
        for (int ks = 0; ks < 2; ks++) {
            short8 af[2];
            #pragma unroll
            for (int mi = 0; mi < 2; mi++) {
                int row = wm + mi * 16 + (lane & 15);
                int off = row * 128 + (((ks * 64) + ((lane >> 4) * 16)) ^ ((row & 7) << 4));
                af[mi] = *(const short8*)((const char*)As + off);
            }
            #pragma unroll
            for (int ni = 0; ni < 4; ni++) {
                int h = wn + ni * 16 + (lane & 15);
                int off = h * 128 + (((ks * 64) + ((lane >> 4) * 16)) ^ ((h & 7) << 4));
                short8 bf1 = *(const short8*)((const char*)Bs1 + off);
                short8 bf2 = *(const short8*)((const char*)Bs2 + off);
                #pragma unroll
                for (int mi = 0; mi < 2; mi++) {
                    c1[mi][ni] = __builtin_amdgcn_mfma_f32_16x16x32_bf16(af[mi], bf1, c1[mi][ni], 0, 0, 0);
                    c2[mi][ni] = __builtin_amdgcn_mfma_f32_16x16x32_bf16(af[mi], bf2, c2[mi][ni], 0, 0, 0);
                }
            }
        }
    }

    float b1v[4], b2v[4];
    #pragma unroll
    for (int ni = 0; ni < 4; ni++) {
        int h = hb + wn + ni * 16 + (lane & 15);
        b1v[ni] = b1[e * HDIM + h];
        b2v[ni] = b2[e * HDIM + h];
    }
    #pragma unroll
    for (int mi = 0; mi < 2; mi++) {
        #pragma unroll
        for (int ni = 0; ni < 4; ni++) {
            int h = hb + wn + ni * 16 + (lane & 15);
            #pragma unroll
            for (int r = 0; r < 4; r++) {
                int m = wm + mi * 16 + (lane >> 4) * 4 + r;
                if (m < nrows) {
                    float h1 = c1[mi][ni][r] + b1v[ni];
                    float h2 = c2[mi][ni][r] + b2v[ni];
                    float g = (h1 / (1.f + expf(-h1))) * h2;
                    gs[(size_t)(p0 + m) * HDIM + h] = f2bf(g);
                }
            }
        }
    }
}

__global__ __launch_bounds__(256) void gemm2_fb(
    const ushort* __restrict__ gs,
    const float* __restrict__ W3, const float* __restrict__ b3,
    const int* __restrict__ cnt, const int* __restrict__ base,
    const int* __restrict__ toklist, const float* __restrict__ wtok,
    float* __restrict__ out)
{
    const int e  = blockIdx.z;
    const int mt = blockIdx.y;
    const int nt = blockIdx.x;
    const int n  = cnt[e];
    if (mt * 64 >= n) return;
    const int nrows = min(64, n - mt * 64);
    const int p0 = base[e] + mt * 64;
    const int db = nt * 256;

    __shared__ alignas(16) ushort As[64 * 64];
    __shared__ alignas(16) ushort Bs[256 * 64];
    __shared__ int   rows[64];
    __shared__ float wr[64];

    const int tid  = threadIdx.x;
    const int lane = tid & 63;
    const int wv   = tid >> 6;
    const int wm   = (wv & 1) * 32;
    const int wn   = (wv >> 1) * 128;

    if (tid < 64) {
        int i = mt * 64 + tid;
        int t = (i < n) ? toklist[e * TOKENS + i] : -1;
        rows[tid] = t;
        wr[tid] = (t >= 0) ? wtok[t] : 0.f;
    }

    f32x4 c[2][8];
    #pragma unroll
    for (int mi = 0; mi < 2; mi++)
        #pragma unroll
        for (int ni = 0; ni < 8; ni++) c[mi][ni] = (f32x4)0.f;

    const size_t ebase = (size_t)e * HDIM * DDIM;

    for (int kb = 0; kb < HDIM; kb += 64) {
        __syncthreads();
        #pragma unroll
        for (int cc = 0; cc < 2; cc++) {
            int s = tid + cc * 256;
            int m = s >> 3, kblk = s & 7;
            uint4 v = *(const uint4*)(gs + (size_t)(p0 + m) * HDIM + kb + kblk * 8);
            int off = m * 128 + ((kblk * 16) ^ ((m & 7) << 4));
            *(uint4*)((char*)As + off) = v;
        }
        #pragma unroll
        for (int ss = 0; ss < 2; ss++) {
            int s = tid + ss * 256;
            int kb8 = (s & 7) * 8;
            int d4  = (s >> 3) * 4;
            union { ushort us[8]; uint4 v; } t3[4];
            #pragma unroll
            for (int kk = 0; kk < 8; kk++) {
                float4 w = *(const float4*)(W3 + ebase + (size_t)(kb + kb8 + kk) * DDIM + db + d4);
                t3[0].us[kk] = f2bf(w.x); t3[1].us[kk] = f2bf(w.y);
                t3[2].us[kk] = f2bf(w.z); t3[3].us[kk] = f2bf(w.w);
            }
            #pragma unroll
            for (int i = 0; i < 4; i++) {
                int d = d4 + i;
                int off = d * 128 + ((kb8 * 2) ^ ((d & 7) << 4));
                *(uint4*)((char*)Bs + off) = t3[i].v;
            }
        }
        __syncthreads();
        #pragma unroll
        for (int ks = 0; ks < 2; ks++) {
            short8 af[2];
            #pragma unroll
            for (int mi = 0; mi < 2; mi++) {
                int row = wm + mi * 16 + (lane & 15);
                int off = row * 128 + (((ks * 64) + ((lane >> 4) * 16)) ^ ((row & 7) << 4));
                af[mi] = *(const short8*)((const char*)As + off);
            }
            #pragma unroll
            for (int ni = 0; ni < 8; ni++) {
                int d = wn + ni * 16 + (lane & 15);
                int off = d * 128 + (((ks * 64) + ((lane >> 4) * 16)) ^ ((d & 7) << 4));
                short8 bf = *(const short8*)((const char*)Bs + off);
                #pragma unroll
                for (int mi = 0; mi < 2; mi++)
                    c[mi][ni] = __builtin_amdgcn_mfma_f32_16x16x32_bf16(af[mi], bf, c[mi][ni], 0, 0, 0);
            }
        }
    }

    float b3v[8];
    #pragma unroll
    for (int ni = 0; ni < 8; ni++)
        b3v[ni] = b3[e * DDIM + db + wn + ni * 16 + (lane & 15)];

    #pragma unroll
    for (int mi = 0; mi < 2; mi++) {
        #pragma unroll
        for (int r = 0; r < 4; r++) {
            int m = wm + mi * 16 + (lane >> 4) * 4 + r;
            if (m < nrows) {
                int t = rows[m];
                float w = wr[m];
                #pragma unroll
                for (int ni = 0; ni < 8; ni++) {
                    int d = db + wn + ni * 16 + (lane & 15);
                    atomicAdd(&out[(size_t)t * DDIM + d], (c[mi][ni][r] + b3v[ni]) * w);
                }
            }
        }
    }
}

extern "C" void kernel_launch(void* const* d_in, const int* in_sizes, int n_in,
                              void* d_out, int out_size, void* d_ws, size_t ws_size,
                              hipStream_t stream) {
    const float* x  = (const float*)d_in[0];
    const float* Wg = (const float*)d_in[1];
    const float* W1 = (const float*)d_in[2];
    const float* b1 = (const float*)d_in[3];
    const float* W2 = (const float*)d_in[4];
    const float* b2 = (const float*)d_in[5];
    const float* W3 = (const float*)d_in[6];
    const float* b3 = (const float*)d_in[7];

    float* out        = (float*)d_out;
    float* out_aux    = out + (size_t)TOKENS * DDIM;
    float* out_scores = out_aux + 1;

    int*   cnt     = (int*)d_ws;
    float* usage   = (float*)d_ws + 8;
    float* zsum    = (float*)d_ws + 16;
    int*   basep   = (int*)d_ws + 20;
    float* wtok    = (float*)d_ws + 32;
    int*   toklist = (int*)d_ws + 32 + TOKENS;
    ushort* xg     = (ushort*)((char*)d_ws + 74752);
    ushort* gsbuf  = (ushort*)((char*)d_ws + 8463360);
    ushort* wb1    = (ushort*)((char*)d_ws + 25240576);
    ushort* wb2    = (ushort*)((char*)d_ws + 58795008);
    ushort* wb3    = (ushort*)((char*)d_ws + 92349440);

    const bool pre = ws_size >= 125903872ull;

    hipMemsetAsync(d_ws, 0, 128, stream);
    hipMemsetAsync(d_out, 0, (size_t)out_size * sizeof(float), stream);

    if (pre) {
        // fused: 512 gate blocks + 1024 page-local convert blocks
        prep_kernel<<<512 + 1024, 256, 0, stream>>>(
            x, Wg, W1, W2, W3, wb1, wb2, wb3,
            out_scores, usage, zsum, cnt, wtok, toklist);
        scan_finalize_kernel<<<1, 64, 0, stream>>>(cnt, basep, usage, zsum, out_aux);

        dim3 gg(32, NEXP);
        gather_kernel<<<gg, 256, 0, stream>>>(x, cnt, basep, toklist, xg);

        dim3 g1(HDIM / 128, 16, NEXP);
        gemm1_pre<<<g1, 512, 0, stream>>>(xg, wb1, wb2, b1, b2, cnt, basep, gsbuf);

        dim3 g2(DDIM / 128, 16, NEXP * 2);
        gemm2_pre<<<g2, 512, 0, stream>>>(gsbuf, wb3, b3, cnt, basep, toklist, wtok, out);
    } else {
        gate_kernel<<<TOKENS / 4, 256, 0, stream>>>(x, Wg, out_scores, usage, zsum,
                                                    cnt, wtok, toklist);
        scan_finalize_kernel<<<1, 64, 0, stream>>>(cnt, basep, usage, zsum, out_aux);

        dim3 gg(32, NEXP);
        gather_kernel<<<gg, 256, 0, stream>>>(x, cnt, basep, toklist, xg);

        dim3 g1(HDIM / 128, TOKENS / 64, NEXP);
        gemm1_fb<<<g1, 256, 0, stream>>>(xg, W1, b1, W2, b2, cnt, basep, gsbuf);

        dim3 g2(DDIM / 256, TOKENS / 64, NEXP);
        gemm2_fb<<<g2, 256, 0, stream>>>(gsbuf, W3, b3, cnt, basep, toklist, wtok, out);
    }
}

// Round 15
// 258.617 us; speedup vs baseline: 1.0736x; 1.0162x over previous
//
#include <hip/hip_runtime.h>
#include <hip/hip_bf16.h>
#include <math.h>

#define TOKENS 2048   // B*S
#define DDIM   1024
#define HDIM   2048
#define NEXP   8

typedef __attribute__((ext_vector_type(8))) short short8;
typedef __attribute__((ext_vector_type(4))) float f32x4;

typedef __attribute__((address_space(3))) unsigned int as3_uint;
typedef __attribute__((address_space(1))) unsigned int as1_uint;

__device__ __forceinline__ void gld16(const void* g, void* l) {
    __builtin_amdgcn_global_load_lds((const as1_uint*)g, (as3_uint*)l, 16, 0, 0);
}

__device__ __forceinline__ ushort f2bf(float f) {
    unsigned u = __float_as_uint(f);
    unsigned r = (u + 0x7fffu + ((u >> 16) & 1u)) >> 16;   // RNE
    return (ushort)r;
}

// ---------------- workspace layout (bytes) ----------------
// 0        : int cnt[8], float usage[8], float zsum, pad, int base[9]  (first 128 zeroed)
// 128      : float wtok[2048]
// 8320     : int toklist[8*2048]
// 74752    : ushort xg[4096*1024]      8,388,608 B
// 8463360  : ushort gs[4096*2048]     16,777,216 B
// 25240576 : ushort wb1 tiles         33,554,432 B  (pre-swizzled 128x64 tiles)
// 58795008 : ushort wb2 tiles         33,554,432 B
// 92349440 : ushort wb3 tiles         33,554,432 B
// end 125,903,872

// ---------------- gate (device body) ----------------
struct GateSmem {
    float sm[4][8];
    float zsm[4];
};

__device__ __forceinline__ void gate_block(
    int bid, GateSmem& gsm,
    const float* __restrict__ x, const float* __restrict__ Wg,
    float* __restrict__ out_scores,
    float* __restrict__ usage, float* __restrict__ zsum,
    int* __restrict__ cnt, float* __restrict__ wtok, int* __restrict__ toklist)
{
    const int lane = threadIdx.x & 63;
    const int wv   = threadIdx.x >> 6;
    const int t    = bid * 4 + wv;

    float acc[8] = {0.f,0.f,0.f,0.f,0.f,0.f,0.f,0.f};
    const float* xr = x + (size_t)t * DDIM;
    for (int d = lane; d < DDIM; d += 64) {
        float xv = xr[d];
        const float* wg = Wg + d * 8;
        #pragma unroll
        for (int e = 0; e < 8; e++) acc[e] += xv * wg[e];
    }
    #pragma unroll
    for (int off = 32; off >= 1; off >>= 1) {
        #pragma unroll
        for (int e = 0; e < 8; e++) acc[e] += __shfl_xor(acc[e], off, 64);
    }

    float mx = acc[0];
    #pragma unroll
    for (int e = 1; e < 8; e++) mx = fmaxf(mx, acc[e]);
    float s[8]; float sum = 0.f;
    #pragma unroll
    for (int e = 0; e < 8; e++) { s[e] = expf(acc[e] - mx); sum += s[e]; }
    float inv = 1.f / sum;
    #pragma unroll
    for (int e = 0; e < 8; e++) s[e] *= inv;
    float lse = mx + logf(sum);

    if (lane == 0) {
        int i0 = 0;
        #pragma unroll
        for (int e = 1; e < 8; e++) if (s[e] > s[i0]) i0 = e;
        int i1 = (i0 == 0) ? 1 : 0;
        #pragma unroll
        for (int e = 0; e < 8; e++) if (e != i0 && s[e] > s[i1]) i1 = e;

        wtok[t] = s[i0] + s[i1];
        #pragma unroll
        for (int e = 0; e < 8; e++) {
            out_scores[(size_t)t * 8 + e] = s[e];
            gsm.sm[wv][e] = s[e];
        }
        gsm.zsm[wv] = lse * lse;

        int p0 = atomicAdd(&cnt[i0], 1);
        toklist[i0 * TOKENS + p0] = t;
        int p1 = atomicAdd(&cnt[i1], 1);
        toklist[i1 * TOKENS + p1] = t;
    }
    __syncthreads();
    if (threadIdx.x < 8) {
        float u = gsm.sm[0][threadIdx.x] + gsm.sm[1][threadIdx.x] +
                  gsm.sm[2][threadIdx.x] + gsm.sm[3][threadIdx.x];
        atomicAdd(&usage[threadIdx.x], u);
    }
    if (threadIdx.x == 8) {
        atomicAdd(zsum, gsm.zsm[0] + gsm.zsm[1] + gsm.zsm[2] + gsm.zsm[3]);
    }
}

// ---------------- convert: 2 adjacent nt tiles (R12 body, tid-parameterized) ----------------
// fp32 [E][K][N] -> bf16 pre-swizzled tiles [e][nt][kt][16KB].
__device__ __forceinline__ void convert2_block(
    int tid, int pr, int kt, int e, ushort* Ls,
    const float* __restrict__ src, ushort* __restrict__ dst, int N, int K)
{
    const int NT = N >> 7, KT = K >> 6;
    const int kb8 = (tid & 7) * 8;
    const int n4  = (tid >> 3) * 4;
    const size_t ebase = (size_t)e * K * N;
    const int nt0 = pr * 2;

    float4 w0[8], w1[8];
    const float* rbase = src + ebase + (size_t)(kt * 64 + kb8) * N + nt0 * 128 + n4;
    #pragma unroll
    for (int kk = 0; kk < 8; kk++) {
        w0[kk] = *(const float4*)(rbase + (size_t)kk * N);
        w1[kk] = *(const float4*)(rbase + (size_t)kk * N + 128);
    }

    union { ushort us[8]; uint4 v; } t0[4], t1[4];
    #pragma unroll
    for (int kk = 0; kk < 8; kk++) {
        t0[0].us[kk] = f2bf(w0[kk].x); t0[1].us[kk] = f2bf(w0[kk].y);
        t0[2].us[kk] = f2bf(w0[kk].z); t0[3].us[kk] = f2bf(w0[kk].w);
        t1[0].us[kk] = f2bf(w1[kk].x); t1[1].us[kk] = f2bf(w1[kk].y);
        t1[2].us[kk] = f2bf(w1[kk].z); t1[3].us[kk] = f2bf(w1[kk].w);
    }
    #pragma unroll
    for (int i = 0; i < 4; i++) {
        int n = n4 + i;
        int off = n * 128 + ((kb8 * 2) ^ ((n & 7) << 4));
        *(uint4*)((char*)Ls + off) = t0[i].v;
        *(uint4*)((char*)Ls + 16384 + off) = t1[i].v;
    }
    __syncthreads();

    #pragma unroll
    for (int j2 = 0; j2 < 2; j2++) {
        char* tb = (char*)dst + (((size_t)(e * NT + nt0 + j2)) * KT + kt) * 16384;
        const char* lsrc = (const char*)Ls + j2 * 16384;
        #pragma unroll
        for (int j = 0; j < 4; j++)
            *(uint4*)(tb + j * 4096 + tid * 16) = *(const uint4*)(lsrc + j * 4096 + tid * 16);
    }
}

// ---------------- fused prep: gate (512) + W1/W2 converts (2048) ----------------
// W3 conversion moved into the gemm1 launch (rides under its latency slack).
__global__ __launch_bounds__(256) void prep_kernel(
    const float* __restrict__ x, const float* __restrict__ Wg,
    const float* __restrict__ W1, const float* __restrict__ W2,
    ushort* __restrict__ wb1, ushort* __restrict__ wb2,
    float* __restrict__ out_scores,
    float* __restrict__ usage, float* __restrict__ zsum,
    int* __restrict__ cnt, float* __restrict__ wtok, int* __restrict__ toklist)
{
    __shared__ union {
        GateSmem g;
        ushort Ls[16384];   // 32KB: two tiles
    } smu;

    const int bid = blockIdx.x;
    if (bid < 512) {                              // gate
        gate_block(bid, smu.g, x, Wg, out_scores, usage, zsum, cnt, wtok, toklist);
    } else if (bid < 512 + 1024) {                // W1: 8 pairs x 16 kt x 8 e
        int b = bid - 512, rem = b & 127;
        convert2_block(threadIdx.x, rem & 7, rem >> 3, b >> 7, smu.Ls, W1, wb1, HDIM, DDIM);
    } else {                                      // W2
        int b = bid - (512 + 1024), rem = b & 127;
        convert2_block(threadIdx.x, rem & 7, rem >> 3, b >> 7, smu.Ls, W2, wb2, HDIM, DDIM);
    }
}

// standalone gate for the fallback path
__global__ __launch_bounds__(256) void gate_kernel(
    const float* __restrict__ x, const float* __restrict__ Wg,
    float* __restrict__ out_scores,
    float* __restrict__ usage, float* __restrict__ zsum,
    int* __restrict__ cnt, float* __restrict__ wtok, int* __restrict__ toklist)
{
    __shared__ GateSmem gsm;
    gate_block(blockIdx.x, gsm, x, Wg, out_scores, usage, zsum, cnt, wtok, toklist);
}

__global__ void scan_finalize_kernel(const int* __restrict__ cnt, int* __restrict__ base,
                                     const float* __restrict__ usage,
                                     const float* __restrict__ zsum,
                                     float* __restrict__ out_aux)
{
    if (threadIdx.x == 0) {
        int b = 0;
        #pragma unroll
        for (int e = 0; e < 8; e++) { base[e] = b; b += cnt[e]; }
        base[8] = b;
        float lb = 0.f;
        #pragma unroll
        for (int e = 0; e < 8; e++) {
            float u = usage[e] / (float)TOKENS;
            lb -= u * logf(u + 1e-9f);
        }
        out_aux[0] = lb + (zsum[0] / (float)TOKENS) * 1e-3f;
    }
}

// gather x rows per (expert, slot) into compacted bf16 xg[pair][1024]
__global__ __launch_bounds__(256) void gather_kernel(
    const float* __restrict__ x, const int* __restrict__ cnt,
    const int* __restrict__ base, const int* __restrict__ toklist,
    ushort* __restrict__ xg)
{
    const int e  = blockIdx.y;
    const int it = blockIdx.x;
    const int n  = cnt[e];
    const int i0 = it * 64;
    if (i0 >= n) return;

    __shared__ int rws[64];
    const int tid = threadIdx.x;
    if (tid < 64) rws[tid] = (i0 + tid < n) ? toklist[e * TOKENS + i0 + tid] : -1;
    __syncthreads();

    const int pbase = base[e] + i0;
    for (int idx = tid; idx < 64 * 256; idx += 256) {
        int r = idx >> 8, c = idx & 255;
        int t = rws[r];
        if (t < 0) continue;
        float4 v = *(const float4*)(x + (size_t)t * DDIM + c * 4);
        union { ushort us[4]; uint2 u; } pk;
        pk.us[0] = f2bf(v.x); pk.us[1] = f2bf(v.y);
        pk.us[2] = f2bf(v.z); pk.us[3] = f2bf(v.w);
        *(uint2*)(xg + (size_t)(pbase + r) * DDIM + c * 4) = pk.u;
    }
}

// ============ preconverted-weight GEMMs ============

// GEMM1 + SwiGLU (R5-proven core, 78us) + fused W3 conversion blocks.
// Grid x: ht<16 -> GEMM tile; ht in [16,20) -> W3 convert (2 pair-units per
// 512-thr block, two 256-thr halves in a 64KB smem union).
__global__ __launch_bounds__(512, 4) void gemm1_pre(
    const ushort* __restrict__ xg,
    const ushort* __restrict__ wb1, const ushort* __restrict__ wb2,
    const float* __restrict__ b1, const float* __restrict__ b2,
    const int* __restrict__ cnt, const int* __restrict__ base,
    ushort* __restrict__ gs,
    const float* __restrict__ W3, ushort* __restrict__ wb3)
{
    __shared__ alignas(16) char smem[65536];   // GEMM: A16|B1 16|B2 16 (48K). Convert: 2x32K.

    const int e  = blockIdx.z;
    const int mt = blockIdx.y;
    const int ht = blockIdx.x;

    if (ht >= 16) {
        // ---- W3 convert rider: unit in [0,512), pair p = 2*unit + half ----
        int unit = (e * 16 + mt) * 4 + (ht - 16);
        int half = threadIdx.x >> 8;
        int p    = unit * 2 + half;            // [0,1024)
        int e3   = p >> 7;
        int rem  = p & 127;
        int kt3  = rem >> 2;
        int pp3  = rem & 3;
        ushort* Ls = (ushort*)(smem + half * 32768);
        convert2_block(threadIdx.x & 255, pp3, kt3, e3, Ls, W3, wb3, DDIM, HDIM);
        return;
    }

    const int n  = cnt[e];
    if (mt * 128 >= n) return;
    const int nrows = min(128, n - mt * 128);
    const int p0 = base[e] + mt * 128;
    const int hb = ht * 128;

    const int tid  = threadIdx.x;
    const int lane = tid & 63;
    const int wv   = tid >> 6;            // 0..7
    const int wm   = (wv & 1) * 64;
    const int wn   = (wv >> 1) * 32;

    f32x4 c1[4][2], c2[4][2];
    #pragma unroll
    for (int mi = 0; mi < 4; mi++)
        #pragma unroll
        for (int ni = 0; ni < 2; ni++) { c1[mi][ni] = (f32x4)0.f; c2[mi][ni] = (f32x4)0.f; }

    const char* t1 = (const char*)wb1 + (size_t)(e * 16 + ht) * (16 * 16384);
    const char* t2 = (const char*)wb2 + (size_t)(e * 16 + ht) * (16 * 16384);

    // A staging role: row ar (0..127), two 8-bf16 groups at kblk akb, akb+1
    const int ar  = tid >> 2;
    const int akb = (tid & 3) * 2;
    const ushort* agp = xg + (size_t)(p0 + ar) * DDIM + akb * 8;
    const int ao0 = ar * 128 + ((akb * 16) ^ ((ar & 7) << 4));
    const int ao1 = ar * 128 + (((akb + 1) * 16) ^ ((ar & 7) << 4));

    uint4 av0, av1, bv0, bv1, bv2, bv3;

#define G1_LOAD(kt) do {                                              \
        av0 = *(const uint4*)(agp + (kt) * 64);                       \
        av1 = *(const uint4*)(agp + (kt) * 64 + 8);                   \
        const char* _p1 = t1 + (size_t)(kt) * 16384 + tid * 16;       \
        const char* _p2 = t2 + (size_t)(kt) * 16384 + tid * 16;       \
        bv0 = *(const uint4*)(_p1);                                   \
        bv1 = *(const uint4*)(_p1 + 8192);                            \
        bv2 = *(const uint4*)(_p2);                                   \
        bv3 = *(const uint4*)(_p2 + 8192);                            \
    } while (0)

#define G1_WRITE() do {                                               \
        *(uint4*)(smem + ao0) = av0;                                  \
        *(uint4*)(smem + ao1) = av1;                                  \
        char* _d = smem + 16384 + tid * 16;                           \
        *(uint4*)(_d)                = bv0;                           \
        *(uint4*)(_d + 8192)         = bv1;                           \
        *(uint4*)(_d + 16384)        = bv2;                           \
        *(uint4*)(_d + 16384 + 8192) = bv3;                           \
    } while (0)

    G1_LOAD(0);
    G1_WRITE();
    __syncthreads();

    for (int kt = 0; kt < 16; kt++) {
        if (kt < 15) G1_LOAD(kt + 1);        // fly under MFMA below

        short8 af[4][2];
        #pragma unroll
        for (int mi = 0; mi < 4; mi++) {
            int row = wm + mi * 16 + (lane & 15);
            #pragma unroll
            for (int ks = 0; ks < 2; ks++) {
                int off = row * 128 + (((ks * 64) + ((lane >> 4) * 16)) ^ ((row & 7) << 4));
                af[mi][ks] = *(const short8*)(smem + off);
            }
        }
        #pragma unroll
        for (int ni = 0; ni < 2; ni++) {
            int h = wn + ni * 16 + (lane & 15);
            #pragma unroll
            for (int ks = 0; ks < 2; ks++) {
                int off = h * 128 + (((ks * 64) + ((lane >> 4) * 16)) ^ ((h & 7) << 4));
                short8 bv1r = *(const short8*)(smem + 16384 + off);
                short8 bv2r = *(const short8*)(smem + 32768 + off);
                #pragma unroll
                for (int mi = 0; mi < 4; mi++) {
                    c1[mi][ni] = __builtin_amdgcn_mfma_f32_16x16x32_bf16(af[mi][ks], bv1r, c1[mi][ni], 0, 0, 0);
                    c2[mi][ni] = __builtin_amdgcn_mfma_f32_16x16x32_bf16(af[mi][ks], bv2r, c2[mi][ni], 0, 0, 0);
                }
            }
        }

        if (kt < 15) {
            __syncthreads();                 // all reads of smem done
            G1_WRITE();                      // regs -> LDS (fast)
            __syncthreads();                 // visible for next iter
        }
    }
#undef G1_LOAD
#undef G1_WRITE

    // ---- epilogue: bias + silu*mul -> gs (bf16), direct scatter ----
    float b1v[2], b2v[2];
    #pragma unroll
    for (int ni = 0; ni < 2; ni++) {
        int h = hb + wn + ni * 16 + (lane & 15);
        b1v[ni] = b1[e * HDIM + h];
        b2v[ni] = b2[e * HDIM + h];
    }
    #pragma unroll
    for (int mi = 0; mi < 4; mi++) {
        #pragma unroll
        for (int ni = 0; ni < 2; ni++) {
            int h = hb + wn + ni * 16 + (lane & 15);
            #pragma unroll
            for (int r = 0; r < 4; r++) {
                int m = wm + mi * 16 + (lane >> 4) * 4 + r;
                if (m < nrows) {
                    float h1 = c1[mi][ni][r] + b1v[ni];
                    float h2 = c2[mi][ni][r] + b2v[ni];
                    float g = (h1 / (1.f + expf(-h1))) * h2;
                    gs[(size_t)(p0 + m) * HDIM + h] = f2bf(g);
                }
            }
        }
    }
}

// GEMM2 (R8-proven): 512 thr, tile 128m x 128d, split-K x2 (16 kt each),
// FULL double-buffer, ONE __syncthreads per K-step, LDS 64KB = 2 x (A16|B16).
__global__ __launch_bounds__(512, 4) void gemm2_pre(
    const ushort* __restrict__ gs,
    const ushort* __restrict__ wb3, const float* __restrict__ b3,
    const int* __restrict__ cnt, const int* __restrict__ base,
    const int* __restrict__ toklist, const float* __restrict__ wtok,
    float* __restrict__ out)
{
    const int e  = blockIdx.z >> 1;
    const int kh = blockIdx.z & 1;
    const int mt = blockIdx.y;
    const int nt = blockIdx.x;
    const int n  = cnt[e];
    if (mt * 128 >= n) return;
    const int nrows = min(128, n - mt * 128);
    const int p0 = base[e] + mt * 128;
    const int db = nt * 128;

    __shared__ alignas(16) char smem[65536];       // buf p at p*32768: A16|B16
    __shared__ int   rows[128];
    __shared__ float wr[128];

    const int tid  = threadIdx.x;
    const int lane = tid & 63;
    const int wv   = tid >> 6;
    const int wm   = (wv & 1) * 64;
    const int wn   = (wv >> 1) * 32;

    if (tid < 128) {
        int i = mt * 128 + tid;
        int t = (i < n) ? toklist[e * TOKENS + i] : -1;
        rows[tid] = t;
        wr[tid] = (t >= 0) ? wtok[t] : 0.f;
    }

    f32x4 c[4][2];
    #pragma unroll
    for (int mi = 0; mi < 4; mi++)
        #pragma unroll
        for (int ni = 0; ni < 2; ni++) c[mi][ni] = (f32x4)0.f;

    const char* t3 = (const char*)wb3 + (size_t)(e * 8 + nt) * (32 * 16384)
                   + (size_t)kh * (16 * 16384);
    const int bgo = wv * 2048 + lane * 16;
    const int bdo = wv * 2048;

    const int ar  = tid >> 2;
    const int akb = (tid & 3) * 2;
    const ushort* agp = gs + (size_t)(p0 + ar) * HDIM + kh * 1024 + akb * 8;
    const int ao0 = ar * 128 + ((akb * 16) ^ ((ar & 7) << 4));
    const int ao1 = ar * 128 + (((akb + 1) * 16) ^ ((ar & 7) << 4));

    uint4 av0, av1;

    // ---- prologue: fill buf0 with tile kt=0 ----
    av0 = *(const uint4*)(agp);
    av1 = *(const uint4*)(agp + 8);
    {
        char* d = smem + 16384 + bdo;
        gld16(t3 + bgo,        d);
        gld16(t3 + bgo + 1024, d + 1024);
    }
    *(uint4*)(smem + ao0) = av0;
    *(uint4*)(smem + ao1) = av1;
    __syncthreads();

    for (int kt = 0; kt < 16; kt++) {
        const int p = kt & 1;
        const char* Ab = smem + p * 32768;
        const char* Bb = Ab + 16384;
        char* Nb = smem + (p ^ 1) * 32768;

        if (kt < 15) {
            av0 = *(const uint4*)(agp + (kt + 1) * 64);
            av1 = *(const uint4*)(agp + (kt + 1) * 64 + 8);
            const size_t go = (size_t)(kt + 1) * 16384 + bgo;
            char* d = Nb + 16384 + bdo;
            gld16(t3 + go,        d);
            gld16(t3 + go + 1024, d + 1024);
        }

        short8 af[4][2];
        #pragma unroll
        for (int mi = 0; mi < 4; mi++) {
            int row = wm + mi * 16 + (lane & 15);
            #pragma unroll
            for (int ks = 0; ks < 2; ks++) {
                int off = row * 128 + (((ks * 64) + ((lane >> 4) * 16)) ^ ((row & 7) << 4));
                af[mi][ks] = *(const short8*)(Ab + off);
            }
        }
        #pragma unroll
        for (int ni = 0; ni < 2; ni++) {
            int d = wn + ni * 16 + (lane & 15);
            #pragma unroll
            for (int ks = 0; ks < 2; ks++) {
                int off = d * 128 + (((ks * 64) + ((lane >> 4) * 16)) ^ ((d & 7) << 4));
                short8 bv = *(const short8*)(Bb + off);
                #pragma unroll
                for (int mi = 0; mi < 4; mi++)
                    c[mi][ni] = __builtin_amdgcn_mfma_f32_16x16x32_bf16(af[mi][ks], bv, c[mi][ni], 0, 0, 0);
            }
        }

        if (kt < 15) {
            *(uint4*)(Nb + ao0) = av0;
            *(uint4*)(Nb + ao1) = av1;
        }
        __syncthreads();
    }

    float b3v[2];
    #pragma unroll
    for (int ni = 0; ni < 2; ni++)
        b3v[ni] = (kh == 0) ? b3[e * DDIM + db + wn + ni * 16 + (lane & 15)] : 0.f;

    #pragma unroll
    for (int mi = 0; mi < 4; mi++) {
        #pragma unroll
        for (int r = 0; r < 4; r++) {
            int m = wm + mi * 16 + (lane >> 4) * 4 + r;
            if (m < nrows) {
                int t = rows[m];
                float w = wr[m];
                #pragma unroll
                for (int ni = 0; ni < 2; ni++) {
                    int d = db + wn + ni * 16 + (lane & 15);
                    atomicAdd(&out[(size_t)t * DDIM + d], (c[mi][ni][r] + b3v[ni]) * w);
                }
            }
        }
    }
}

// ============ fallback (on-the-fly conversion) GEMMs — R2 versions ============

__global__ __launch_bounds__(256) void gemm1_fb(
    const ushort* __restrict__ xg,
    const float* __restrict__ W1, const float* __restrict__ b1,
    const float* __restrict__ W2, const float* __restrict__ b2,
    const int* __restrict__ cnt, const int* __restrict__ base,
    ushort* __restrict__ gs)
{
    const int e  = blockIdx.z;
    const int mt = blockIdx.y;
    const int ht = blockIdx.x;
    const int n  = cnt[e];
    if (mt * 64 >= n) return;
    const int nrows = min(64, n - mt * 64);
    const int p0 = base[e] + mt * 64;
    const int hb = ht * 128;

    __shared__ alignas(16) ushort As[64 * 64];
    __shared__ alignas(16) ushort Bs1[128 * 64];
    __shared__ alignas(16) ushort Bs2[128 * 64];

    const int tid  = threadIdx.x;
    const int lane = tid & 63;
    const int wv   = tid >> 6;
    const int wm   = (wv & 1) * 32;
    const int wn   = (wv >> 1) * 64;

    f32x4 c1[2][4], c2[2][4];
    #pragma unroll
    for (int mi = 0; mi < 2; mi++)
        #pragma unroll
        for (int ni = 0; ni < 4; ni++) { c1[mi][ni] = (f32x4)0.f; c2[mi][ni] = (f32x4)0.f; }

    const size_t ebase = (size_t)e * DDIM * HDIM;
    const int kb8 = (tid & 7) * 8;
    const int h4  = (tid >> 3) * 4;

    for (int kb = 0; kb < DDIM; kb += 64) {
        __syncthreads();
        #pragma unroll
        for (int c = 0; c < 2; c++) {
            int s = tid + c * 256;
            int m = s >> 3, kblk = s & 7;
            uint4 v = *(const uint4*)(xg + (size_t)(p0 + m) * DDIM + kb + kblk * 8);
            int off = m * 128 + ((kblk * 16) ^ ((m & 7) << 4));
            *(uint4*)((char*)As + off) = v;
        }
        {
            union { ushort us[8]; uint4 v; } t1[4], t2[4];
            #pragma unroll
            for (int kk = 0; kk < 8; kk++) {
                const size_t ro = ebase + (size_t)(kb + kb8 + kk) * HDIM + hb + h4;
                float4 w1 = *(const float4*)(W1 + ro);
                float4 w2 = *(const float4*)(W2 + ro);
                t1[0].us[kk] = f2bf(w1.x); t1[1].us[kk] = f2bf(w1.y);
                t1[2].us[kk] = f2bf(w1.z); t1[3].us[kk] = f2bf(w1.w);
                t2[0].us[kk] = f2bf(w2.x); t2[1].us[kk] = f2bf(w2.y);
                t2[2].us[kk] = f2bf(w2.z); t2[3].us[kk] = f2bf(w2.w);
            }
            #pragma unroll
            for (int i = 0; i < 4; i++) {
                int h = h4 + i;
                int off = h * 128 + ((kb8 * 2) ^ ((h & 7) << 4));
                *(uint4*)((char*)Bs1 + off) = t1[i].v;
                *(uint4*)((char*)Bs2 + off) = t2[i].v;
            }
        }
        __syncthreads();
        #pragma unroll
        for (int ks = 0; ks < 2; ks++) {
            short8 af[2];
            #pragma unroll
            for (int mi = 0; mi < 2; mi++) {
                int row = wm + mi * 16 + (lane & 15);
                int off = row * 128 + (((ks * 64) + ((lane >> 4) * 16)) ^ ((row & 7) << 4));
                af[mi] = *(const short8*)((const char*)As + off);
            }
            #pragma unroll
            for (int ni = 0; ni < 4; ni++) {
                int h = wn + ni * 16 + (lane & 15);
                int off = h * 128 + (((ks * 64) + ((lane >> 4) * 16)) ^ ((h & 7) << 4));
                short8 bf1 = *(const short8*)((const char*)Bs1 + off);
                short8 bf2 = *(const short8*)((const char*)Bs2 + off);
                #pragma unroll
                for (int mi = 0; mi < 2; mi++) {
                    c1[mi][ni] = __builtin_amdgcn_mfma_f32_16x16x32_bf16(af[mi], bf1, c1[mi][ni], 0, 0, 0);
                    c2[mi][ni] = __builtin_amdgcn_mfma_f32_16x16x32_bf16(af[mi], bf2, c2[mi][ni], 0, 0, 0);
                }
            }
        }
    }

    float b1v[4], b2v[4];
    #pragma unroll
    for (int ni = 0; ni < 4; ni++) {
        int h = hb + wn + ni * 16 + (lane & 15);
        b1v[ni] = b1[e * HDIM + h];
        b2v[ni] = b2[e * HDIM + h];
    }
    #pragma unroll
    for (int mi = 0; mi < 2; mi++) {
        #pragma unroll
        for (int ni = 0; ni < 4; ni++) {
            int h = hb + wn + ni * 16 + (lane & 15);
            #pragma unroll
            for (int r = 0; r < 4; r++) {
                int m = wm + mi * 16 + (lane >> 4) * 4 + r;
                if (m < nrows) {
                    float h1 = c1[mi][ni][r] + b1v[ni];
                    float h2 = c2[mi][ni][r] + b2v[ni];
                    float g = (h1 / (1.f + expf(-h1))) * h2;
                    gs[(size_t)(p0 + m) * HDIM + h] = f2bf(g);
                }
            }
        }
    }
}

__global__ __launch_bounds__(256) void gemm2_fb(
    const ushort* __restrict__ gs,
    const float* __restrict__ W3, const float* __restrict__ b3,
    const int* __restrict__ cnt, const int* __restrict__ base,
    const int* __restrict__ toklist, const float* __restrict__ wtok,
    float* __restrict__ out)
{
    const int e  = blockIdx.z;
    const int mt = blockIdx.y;
    const int nt = blockIdx.x;
    const int n  = cnt[e];
    if (mt * 64 >= n) return;
    const int nrows = min(64, n - mt * 64);
    const int p0 = base[e] + mt * 64;
    const int db = nt * 256;

    __shared__ alignas(16) ushort As[64 * 64];
    __shared__ alignas(16) ushort Bs[256 * 64];
    __shared__ int   rows[64];
    __shared__ float wr[64];

    const int tid  = threadIdx.x;
    const int lane = tid & 63;
    const int wv   = tid >> 6;
    const int wm   = (wv & 1) * 32;
    const int wn   = (wv >> 1) * 128;

    if (tid < 64) {
        int i = mt * 64 + tid;
        int t = (i < n) ? toklist[e * TOKENS + i] : -1;
        rows[tid] = t;
        wr[tid] = (t >= 0) ? wtok[t] : 0.f;
    }

    f32x4 c[2][8];
    #pragma unroll
    for (int mi = 0; mi < 2; mi++)
        #pragma unroll
        for (int ni = 0; ni < 8; ni++) c[mi][ni] = (f32x4)0.f;

    const size_t ebase = (size_t)e * HDIM * DDIM;

    for (int kb = 0; kb < HDIM; kb += 64) {
        __syncthreads();
        #pragma unroll
        for (int cc = 0; cc < 2; cc++) {
            int s = tid + cc * 256;
            int m = s >> 3, kblk = s & 7;
            uint4 v = *(const uint4*)(gs + (size_t)(p0 + m) * HDIM + kb + kblk * 8);
            int off = m * 128 + ((kblk * 16) ^ ((m & 7) << 4));
            *(uint4*)((char*)As + off) = v;
        }
        #pragma unroll
        for (int ss = 0; ss < 2; ss++) {
            int s = tid + ss * 256;
            int kb8 = (s & 7) * 8;
            int d4  = (s >> 3) * 4;
            union { ushort us[8]; uint4 v; } t3[4];
            #pragma unroll
            for (int kk = 0; kk < 8; kk++) {
                float4 w = *(const float4*)(W3 + ebase + (size_t)(kb + kb8 + kk) * DDIM + db + d4);
                t3[0].us[kk] = f2bf(w.x); t3[1].us[kk] = f2bf(w.y);
                t3[2].us[kk] = f2bf(w.z); t3[3].us[kk] = f2bf(w.w);
            }
            #pragma unroll
            for (int i = 0; i < 4; i++) {
                int d = d4 + i;
                int off = d * 128 + ((kb8 * 2) ^ ((d & 7) << 4));
                *(uint4*)((char*)Bs + off) = t3[i].v;
            }
        }
        __syncthreads();
        #pragma unroll
        for (int ks = 0; ks < 2; ks++) {
            short8 af[2];
            #pragma unroll
            for (int mi = 0; mi < 2; mi++) {
                int row = wm + mi * 16 + (lane & 15);
                int off = row * 128 + (((ks * 64) + ((lane >> 4) * 16)) ^ ((row & 7) << 4));
                af[mi] = *(const short8*)((const char*)As + off);
            }
            #pragma unroll
            for (int ni = 0; ni < 8; ni++) {
                int d = wn + ni * 16 + (lane & 15);
                int off = d * 128 + (((ks * 64) + ((lane >> 4) * 16)) ^ ((d & 7) << 4));
                short8 bf = *(const short8*)((const char*)Bs + off);
                #pragma unroll
                for (int mi = 0; mi < 2; mi++)
                    c[mi][ni] = __builtin_amdgcn_mfma_f32_16x16x32_bf16(af[mi], bf, c[mi][ni], 0, 0, 0);
            }
        }
    }

    float b3v[8];
    #pragma unroll
    for (int ni = 0; ni < 8; ni++)
        b3v[ni] = b3[e * DDIM + db + wn + ni * 16 + (lane & 15)];

    #pragma unroll
    for (int mi = 0; mi < 2; mi++) {
        #pragma unroll
        for (int r = 0; r < 4; r++) {
            int m = wm + mi * 16 + (lane >> 4) * 4 + r;
            if (m < nrows) {
                int t = rows[m];
                float w = wr[m];
                #pragma unroll
                for (int ni = 0; ni < 8; ni++) {
                    int d = db + wn + ni * 16 + (lane & 15);
                    atomicAdd(&out[(size_t)t * DDIM + d], (c[mi][ni][r] + b3v[ni]) * w);
                }
            }
        }
    }
}

extern "C" void kernel_launch(void* const* d_in, const int* in_sizes, int n_in,
                              void* d_out, int out_size, void* d_ws, size_t ws_size,
                              hipStream_t stream) {
    const float* x  = (const float*)d_in[0];
    const float* Wg = (const float*)d_in[1];
    const float* W1 = (const float*)d_in[2];
    const float* b1 = (const float*)d_in[3];
    const float* W2 = (const float*)d_in[4];
    const float* b2 = (const float*)d_in[5];
    const float* W3 = (const float*)d_in[6];
    const float* b3 = (const float*)d_in[7];

    float* out        = (float*)d_out;
    float* out_aux    = out + (size_t)TOKENS * DDIM;
    float* out_scores = out_aux + 1;

    int*   cnt     = (int*)d_ws;
    float* usage   = (float*)d_ws + 8;
    float* zsum    = (float*)d_ws + 16;
    int*   basep   = (int*)d_ws + 20;
    float* wtok    = (float*)d_ws + 32;
    int*   toklist = (int*)d_ws + 32 + TOKENS;
    ushort* xg     = (ushort*)((char*)d_ws + 74752);
    ushort* gsbuf  = (ushort*)((char*)d_ws + 8463360);
    ushort* wb1    = (ushort*)((char*)d_ws + 25240576);
    ushort* wb2    = (ushort*)((char*)d_ws + 58795008);
    ushort* wb3    = (ushort*)((char*)d_ws + 92349440);

    const bool pre = ws_size >= 125903872ull;

    hipMemsetAsync(d_ws, 0, 128, stream);
    hipMemsetAsync(d_out, 0, (size_t)out_size * sizeof(float), stream);

    if (pre) {
        // prep: 512 gate + 2048 W1/W2 convert blocks (W3 rides in gemm1)
        prep_kernel<<<512 + 2048, 256, 0, stream>>>(
            x, Wg, W1, W2, wb1, wb2,
            out_scores, usage, zsum, cnt, wtok, toklist);
        scan_finalize_kernel<<<1, 64, 0, stream>>>(cnt, basep, usage, zsum, out_aux);

        dim3 gg(32, NEXP);
        gather_kernel<<<gg, 256, 0, stream>>>(x, cnt, basep, toklist, xg);

        // gemm1 + W3-convert riders: x-dim 16 GEMM tiles + 4 convert slots
        dim3 g1(16 + 4, 16, NEXP);
        gemm1_pre<<<g1, 512, 0, stream>>>(xg, wb1, wb2, b1, b2, cnt, basep, gsbuf,
                                          W3, wb3);

        dim3 g2(DDIM / 128, 16, NEXP * 2);
        gemm2_pre<<<g2, 512, 0, stream>>>(gsbuf, wb3, b3, cnt, basep, toklist, wtok, out);
    } else {
        gate_kernel<<<TOKENS / 4, 256, 0, stream>>>(x, Wg, out_scores, usage, zsum,
                                                    cnt, wtok, toklist);
        scan_finalize_kernel<<<1, 64, 0, stream>>>(cnt, basep, usage, zsum, out_aux);

        dim3 gg(32, NEXP);
        gather_kernel<<<gg, 256, 0, stream>>>(x, cnt, basep, toklist, xg);

        dim3 g1(HDIM / 128, TOKENS / 64, NEXP);
        gemm1_fb<<<g1, 256, 0, stream>>>(xg, W1, b1, W2, b2, cnt, basep, gsbuf);

        dim3 g2(DDIM / 256, TOKENS / 64, NEXP);
        gemm2_fb<<<g2, 256, 0, stream>>>(gsbuf, W3, b3, cnt, basep, toklist, wtok, out);
    }
}